// Round 3
// baseline (861.892 us; speedup 1.0000x reference)
//
#include <hip/hip_runtime.h>
#include <math.h>

// Problem constants
#define NN      65536
#define GG      64
#define NPG     1024
#define KEIG    32
#define NBUN    64
#define BDIM    4
#define CH      256        // IN_CH == GNN_DIM == NB*BD
#define NBP     384
#define NEDGE   524288

using f16x8 = __attribute__((ext_vector_type(8))) _Float16;
using f16x4 = __attribute__((ext_vector_type(4))) _Float16;
using f32x4 = __attribute__((ext_vector_type(4))) float;

__device__ __forceinline__ float gelu_f(float x) {
    return 0.5f * x * (1.0f + erff(x * 0.70710678118654752440f));
}

// ---------------------------------------------------------------------------
// fp16 MFMA GEMM, LDS-FREE: C = post( A[M,KTOT] @ W ), W as Wt[NOUT,KTOT].
// R2 finding: global_load_lds DMA caps ~1 TB/s; direct global->VGPR fragment
// loads reach 2.86 TB/s. R2 flaw: waves stacked in M + grid.x over n-panels
// re-fetched each A-panel 4x from HBM (sibling blocks on different XCDs; L3
// didn't merge; FETCH 270 MB, traffic-bound 108 us = 310MB/2.86TBps).
// R3: waves stacked in N. Block = 64 A-rows x NOUT cols (4 waves x 64 cols;
// 6 waves for NOUT=384). All waves of a CU load the SAME A fragments -> L1
// serves the redundancy; each A-panel fetched from HBM exactly once. B panel
// (<=256KB) is L2-resident per XCD. Per-wave inner loop identical to R2:
// fragment = 16B/lane at (row=lane&15, kchunk=lane>>4) == global_load_dwordx4,
// 3-stage register pipeline, no LDS, no barriers.
// DUAL: A = concat_k(A1, A2), KTOT=512.
// RESA: + (float)A1[m,n] residual, read-only (requires NOUT==256).
// WF: write fp32 Cf.  W16: write fp16 C16.
// Outputs disjoint from ALL inputs (graph-replay safety).
// ---------------------------------------------------------------------------
template<int NOUT, int KTOT, bool DUAL, bool ACT, bool RESA, bool WF, bool W16>
__global__ __launch_bounds__((NOUT % 256) ? 384 : 256, 2) void mgemm_k(
    const _Float16* __restrict__ A1, const _Float16* __restrict__ A2,
    const _Float16* __restrict__ Wt, const float* __restrict__ bias,
    float* __restrict__ Cf, _Float16* __restrict__ C16)
{
    const int tid  = threadIdx.x;
    const int lane = tid & 63;
    const int wave = tid >> 6;
    const int m0   = blockIdx.y * 64;    // block's 64 A-rows (shared by waves)
    const int n0   = wave * 64;          // wave's 64 output cols

    const int r16 = lane & 15;   // row (A) / col (B) within 16
    const int kc  = lane >> 4;   // k-chunk 0..3 (8 halfs each)

    // per-thread fragment base pointers (element units); A rows are 256 wide
    const _Float16* a1p = A1 + (size_t)(m0 + r16) * 256 + kc * 8;
    const _Float16* a2p = DUAL ? (A2 + (size_t)(m0 + r16) * 256 + kc * 8) : A1;
    const _Float16* bp  = Wt + (size_t)(n0 + r16) * KTOT + kc * 8;

    constexpr int NT = KTOT / 32;   // 8 or 16 K-steps

    f16x8 af[3][4], bf[3][4];       // 3-stage pipeline, static indices only
    f32x4 acc[4][4];
#pragma unroll
    for (int i = 0; i < 4; i++)
#pragma unroll
        for (int j = 0; j < 4; j++) acc[i][j] = 0.f;

#define LDA(T, S)                                                              \
    {                                                                          \
        const _Float16* ap_ = (DUAL && (T) >= 8) ? (a2p + ((T) - 8) * 32)      \
                                                 : (a1p + (T) * 32);           \
        _Pragma("unroll")                                                      \
        for (int q = 0; q < 4; q++)                                            \
            af[(S)][q] = *(const f16x8*)(ap_ + (size_t)q * 16 * 256);          \
        _Pragma("unroll")                                                      \
        for (int q = 0; q < 4; q++)                                            \
            bf[(S)][q] = *(const f16x8*)(bp + (T) * 32 + (size_t)q * 16 * KTOT); \
    }

    LDA(0, 0)
    LDA(1, 1)
    LDA(2, 2)

#pragma unroll
    for (int t = 0; t < NT; ++t) {
        const int s = t % 3;        // compile-time after full unroll
#pragma unroll
        for (int mt = 0; mt < 4; mt++)
#pragma unroll
            for (int nt = 0; nt < 4; nt++)
                acc[mt][nt] = __builtin_amdgcn_mfma_f32_16x16x32_f16(
                    af[s][mt], bf[s][nt], acc[mt][nt], 0, 0, 0);
        if (t + 3 < NT) LDA(t + 3, s)
    }
#undef LDA

    // epilogue: C[m = quad*4+reg][n = lane&15] per 16x16 tile (m89 layout)
    const int rbase = (lane >> 4) * 4;
    const int ncol  = lane & 15;
#pragma unroll
    for (int nt = 0; nt < 4; nt++) {
        const int n = n0 + nt * 16 + ncol;
        const float bs = bias[n];
#pragma unroll
        for (int mt = 0; mt < 4; mt++) {
#pragma unroll
            for (int i = 0; i < 4; i++) {
                const int m = m0 + mt * 16 + rbase + i;
                const size_t idx = (size_t)m * NOUT + n;
                float v = acc[mt][nt][i] + bs;
                if (ACT) v = gelu_f(v);
                if (RESA) v += (float)A1[(size_t)m * 256 + n];
                if (WF) Cf[idx] = v;
                if (W16) C16[idx] = (_Float16)v;
            }
        }
    }
}

// ---------------------------------------------------------------------------
__global__ void zero_k(float* __restrict__ p, size_t n)
{
    size_t i = (size_t)blockIdx.x * blockDim.x + threadIdx.x;
    float4* p4 = (float4*)p;
    size_t n4 = n >> 2;
    for (size_t j = i; j < n4; j += (size_t)gridDim.x * blockDim.x)
        p4[j] = make_float4(0.f, 0.f, 0.f, 0.f);
}

// fp32 -> fp16 convert (4 elems/thread)
__global__ __launch_bounds__(256) void cvt16_k(
    const float* __restrict__ in, _Float16* __restrict__ out)
{
    size_t i = (size_t)blockIdx.x * 256 + threadIdx.x;
    float4 v = ((const float4*)in)[i];
    f16x4 o = { (_Float16)v.x, (_Float16)v.y, (_Float16)v.z, (_Float16)v.w };
    ((f16x4*)out)[i] = o;
}

// weight transpose+convert: Wt[n*ldw + koff + k] = f16(W[k*N + n]); K=256
__global__ __launch_bounds__(256) void twt16_k(
    const float* __restrict__ W, _Float16* __restrict__ Wt,
    int N, int ldw, int koff)
{
    int i = blockIdx.x * 256 + threadIdx.x;   // over 256*N
    int k = i & 255, n = i >> 8;
    if (n < N) Wt[(size_t)n * ldw + koff + k] = (_Float16)W[(size_t)k * N + n];
}

__global__ void bcomb_k(const float* __restrict__ a, const float* __restrict__ b,
                        float* __restrict__ o)
{
    int i = blockIdx.x * 256 + threadIdx.x;
    if (i < 512) o[i] = a[i] + b[i];
}

// ---------------------------------------------------------------------------
// CSR build: histogram of dst, exclusive scan, cursor fill
// ---------------------------------------------------------------------------
__global__ __launch_bounds__(256) void hist_k(const int* __restrict__ ei, int* __restrict__ deg)
{
    int e = blockIdx.x * 256 + threadIdx.x;
    if (e < NEDGE) atomicAdd(&deg[ei[NEDGE + e]], 1);
}

__global__ __launch_bounds__(1024) void scan_k(
    const int* __restrict__ deg, int* __restrict__ off, int* __restrict__ cursor)
{
    __shared__ int sh[1024];
    const int tid = threadIdx.x;
    const int base = tid * 64;
    int s = 0;
#pragma unroll 8
    for (int i = 0; i < 64; i++) s += deg[base + i];
    const int mysum = s;
    sh[tid] = s;
    __syncthreads();
    for (int ofs = 1; ofs < 1024; ofs <<= 1) {
        int v = (tid >= ofs) ? sh[tid - ofs] : 0;
        __syncthreads();
        sh[tid] += v;
        __syncthreads();
    }
    int running = sh[tid] - mysum;
    for (int i = 0; i < 64; i++) {
        off[base + i] = running;
        cursor[base + i] = running;
        running += deg[base + i];
    }
    if (tid == 1023) off[NN] = running;
}

__global__ __launch_bounds__(256) void fill_k(
    const int* __restrict__ ei, int* __restrict__ cursor, int* __restrict__ csr)
{
    int e = blockIdx.x * 256 + threadIdx.x;
    if (e < NEDGE) {
        int d = ei[NEDGE + e];
        int pos = atomicAdd(&cursor[d], 1);
        csr[pos] = ei[e];   // src
    }
}

// ---------------------------------------------------------------------------
// Gather segment-sum over fp16 h: fp32 accum, fp16 out
// ---------------------------------------------------------------------------
__global__ __launch_bounds__(256) void gather16_k(
    const _Float16* __restrict__ h, const int* __restrict__ off,
    const int* __restrict__ csr, _Float16* __restrict__ agg)
{
    const int lane = threadIdx.x & 63;
    const int n = blockIdx.x * 4 + (threadIdx.x >> 6);
    const int s0 = off[n], s1 = off[n + 1];
    float a0 = 0.f, a1 = 0.f, a2 = 0.f, a3 = 0.f;
    int j = s0;
    for (; j + 1 < s1; j += 2) {
        f16x4 va = ((const f16x4*)(h + (size_t)csr[j] * CH))[lane];
        f16x4 vb = ((const f16x4*)(h + (size_t)csr[j + 1] * CH))[lane];
        a0 += (float)va[0] + (float)vb[0]; a1 += (float)va[1] + (float)vb[1];
        a2 += (float)va[2] + (float)vb[2]; a3 += (float)va[3] + (float)vb[3];
    }
    if (j < s1) {
        f16x4 va = ((const f16x4*)(h + (size_t)csr[j] * CH))[lane];
        a0 += (float)va[0]; a1 += (float)va[1]; a2 += (float)va[2]; a3 += (float)va[3];
    }
    f16x4 o = { (_Float16)a0, (_Float16)a1, (_Float16)a2, (_Float16)a3 };
    ((f16x4*)(agg + (size_t)n * CH))[lane] = o;
}

// ---------------------------------------------------------------------------
// Householder Q from 6 fp16 params (BD=4: 3 reflectors)
// ---------------------------------------------------------------------------
__device__ __forceinline__ void make_Q(const _Float16* __restrict__ p, float Q[4][4])
{
#pragma unroll
    for (int i = 0; i < 4; i++)
#pragma unroll
        for (int j = 0; j < 4; j++) Q[i][j] = (i == j) ? 1.f : 0.f;
    int idx = 0;
#pragma unroll
    for (int j = 0; j < 3; j++) {
        float v[4] = {0.f, 0.f, 0.f, 0.f};
        v[j] = 1.f;
#pragma unroll
        for (int t = 0; t < 4; t++)
            if (t > j) v[t] = (float)p[idx + t - (j + 1)];
        idx += 3 - j;
        float nrm = v[0]*v[0] + v[1]*v[1] + v[2]*v[2] + v[3]*v[3];
        float s = 2.f / nrm;
#pragma unroll
        for (int i = 0; i < 4; i++) {
            float qv = Q[i][0]*v[0] + Q[i][1]*v[1] + Q[i][2]*v[2] + Q[i][3]*v[3];
            float t0 = s * qv;
#pragma unroll
            for (int c = 0; c < 4; c++) Q[i][c] -= t0 * v[c];
        }
    }
}

// Bundle transform: block = 4 nodes x 64 bundles; node_rep is fp16
template<bool TRANS>
__global__ __launch_bounds__(256) void bundle_k(
    const float* __restrict__ vin, const _Float16* __restrict__ nr,
    float* __restrict__ out)
{
    __shared__ _Float16 pb[4 * NBP];
    const int n0 = blockIdx.x * 4;
    for (int i = threadIdx.x; i < 4 * NBP; i += 256)
        pb[i] = nr[(size_t)n0 * NBP + i];
    __syncthreads();
    const int ln = threadIdx.x >> 6;
    const int b  = threadIdx.x & 63;
    const int n  = n0 + ln;
    float Q[4][4];
    make_Q(&pb[ln * NBP + b * 6], Q);
    float4 xv = ((const float4*)(vin + (size_t)n * CH))[b];
    float in0 = xv.x, in1 = xv.y, in2 = xv.z, in3 = xv.w;
    float4 o;
    if constexpr (!TRANS) {
        o.x = Q[0][0]*in0 + Q[0][1]*in1 + Q[0][2]*in2 + Q[0][3]*in3;
        o.y = Q[1][0]*in0 + Q[1][1]*in1 + Q[1][2]*in2 + Q[1][3]*in3;
        o.z = Q[2][0]*in0 + Q[2][1]*in1 + Q[2][2]*in2 + Q[2][3]*in3;
        o.w = Q[3][0]*in0 + Q[3][1]*in1 + Q[3][2]*in2 + Q[3][3]*in3;
    } else {
        o.x = Q[0][0]*in0 + Q[1][0]*in1 + Q[2][0]*in2 + Q[3][0]*in3;
        o.y = Q[0][1]*in0 + Q[1][1]*in1 + Q[2][1]*in2 + Q[3][1]*in3;
        o.z = Q[0][2]*in0 + Q[1][2]*in1 + Q[2][2]*in2 + Q[3][2]*in3;
        o.w = Q[0][3]*in0 + Q[1][3]*in1 + Q[2][3]*in2 + Q[3][3]*in3;
    }
    ((float4*)(out + (size_t)n * CH))[b] = o;
}

// ---------------------------------------------------------------------------
// Spectral kernels
// ---------------------------------------------------------------------------
__global__ __launch_bounds__(256) void spec_proj_k(
    const float* __restrict__ v, const float* __restrict__ eigvec, float* __restrict__ hs)
{
    const int g = blockIdx.x;
    const int nbase = g * NPG + blockIdx.y * 128;
    __shared__ float evs[16][32];
    float acc[32];
#pragma unroll
    for (int k = 0; k < 32; k++) acc[k] = 0.f;
    for (int nt = 0; nt < 128; nt += 16) {
        __syncthreads();
        for (int i = threadIdx.x; i < 512; i += 256) {
            int nn = i >> 5, kk = i & 31;
            evs[nn][kk] = eigvec[(size_t)(nbase + nt + nn) * KEIG + kk];
        }
        __syncthreads();
#pragma unroll 4
        for (int nn = 0; nn < 16; nn++) {
            float hv = v[(size_t)(nbase + nt + nn) * CH + threadIdx.x];
#pragma unroll
            for (int k = 0; k < 32; k++) acc[k] += evs[nn][k] * hv;
        }
    }
    float* o = hs + (size_t)g * KEIG * CH + threadIdx.x;
#pragma unroll
    for (int k = 0; k < 32; k++) atomicAdd(o + k * CH, acc[k]);
}

// out16[g,n,d] = sum_v ev[g,n,v] * hs[g,v,d] * exp(-eigval[g,v]*taus[d>>2])
// (spec_scale fused into the hs load)
__global__ __launch_bounds__(256) void spec_reproj16_k(
    const float* __restrict__ eigvec, const float* __restrict__ hs,
    const float* __restrict__ eigval, const float* __restrict__ taus,
    _Float16* __restrict__ out16)
{
    const int g = blockIdx.x >> 4;
    const int nbase = g * NPG + (blockIdx.x & 15) * 64;
    const float tau = taus[threadIdx.x >> 2];
    float hsr[32];
    const float* hg = hs + (size_t)g * KEIG * CH + threadIdx.x;
#pragma unroll
    for (int k = 0; k < 32; k++)
        hsr[k] = hg[k * CH] * expf(-eigval[g * KEIG + k] * tau);
    __shared__ float evs[64][32];
    for (int i = threadIdx.x; i < 2048; i += 256) {
        int nn = i >> 5, kk = i & 31;
        evs[nn][kk] = eigvec[(size_t)(nbase + nn) * KEIG + kk];
    }
    __syncthreads();
    for (int nn = 0; nn < 64; nn++) {
        float a = 0.f;
#pragma unroll
        for (int k = 0; k < 32; k++) a += evs[nn][k] * hsr[k];
        out16[(size_t)(nbase + nn) * CH + threadIdx.x] = (_Float16)a;
    }
}

// ---------------------------------------------------------------------------
extern "C" void kernel_launch(void* const* d_in, const int* in_sizes, int n_in,
                              void* d_out, int out_size, void* d_ws, size_t ws_size,
                              hipStream_t stream)
{
    const float* x      = (const float*)d_in[0];
    const float* eigvec = (const float*)d_in[1];
    const float* eigval = (const float*)d_in[2];
    const float* taus   = (const float*)d_in[3];
    const float* enc_w  = (const float*)d_in[4];
    const float* enc_b  = (const float*)d_in[5];
    const float* self_w = (const float*)d_in[6];
    const float* self_b = (const float*)d_in[7];
    const float* nb_w   = (const float*)d_in[8];
    const float* nb_b   = (const float*)d_in[9];
    const float* dec_w  = (const float*)d_in[10];
    const float* dec_b  = (const float*)d_in[11];
    const float* lin_w  = (const float*)d_in[12];
    const float* lin_b  = (const float*)d_in[13];
    const int*   ei     = (const int*)d_in[14];
    (void)in_sizes; (void)n_in; (void)out_size; (void)ws_size;

    float* ws = (float*)d_ws;
    // fp16 [NN,256] plane = 16,777,216 halfs = 8,388,608 FLOAT-SLOTS (round-6
    // bug: was sized 4,194,304 -> agg stomped CSR -> wild gathers -> fault).
    // Stream-ordered lifetimes (float-slot offsets):
    //  [0,        8388608)  x16          -> vf1[0:half] / h3
    //  [8388608, 16777216)  h0           -> vf1[half:]  / h3
    //  [16777216,25165824)  h1           -> hs (@16.7M) ; free tail
    //  [25165824,33554432)  agg          -> nr16 part
    //  [33554432,34275329)  CSR ints     -> nr16 part
    //  [25165824,37748736)  nr16 [NN,384] fp16 (dec out; agg+CSR dead)
    //  [37748752,37995024)  weights + lbias
    //  [37995024,46383632)  h2 [NN,256] fp16
    // high-water: 46,383,632 fl = 185.5 MB
    _Float16* x16 = (_Float16*)(ws);
    _Float16* h0  = (_Float16*)(ws + 8388608);
    _Float16* h1  = (_Float16*)(ws + 16777216);
    _Float16* agg = (_Float16*)(ws + 25165824);
    int* ibase  = (int*)(ws + 33554432);
    int* deg    = ibase;                 // NN
    int* off    = ibase + 65536;         // NN+1
    int* cursor = ibase + 131073;        // NN
    int* csr    = ibase + 196609;        // NEDGE (ends slot 34275329)
    _Float16* nr16 = (_Float16*)(ws + 25165824);  // [NN,384] fp16
    float* wb = ws + 37748752;
    _Float16* enc16 = (_Float16*)(wb);            // [256,256]
    _Float16* l1w   = (_Float16*)(wb + 32768);    // [256,512]
    _Float16* l2w   = (_Float16*)(wb + 98304);    // [256,512]
    _Float16* dec16 = (_Float16*)(wb + 163840);   // [384,256]
    _Float16* lin16 = (_Float16*)(wb + 212992);   // [256,256]
    float* lbias = wb + 245760;                   // [2,256] (ends wb+246272)
    _Float16* h2 = (_Float16*)(ws + 37995024);    // [NN,256] fp16
    float* vf1 = ws;                              // [NN,256] fp32 (x16,h0 dead)
    float* hs  = ws + 16777216;                   // [64,32,256] fp32 (h1 dead)
    float* h3  = vf1;                             // vf1 dead after spec_proj

    dim3 blk(256);

    // ---- prep ----
    cvt16_k<<<16384, blk, 0, stream>>>(x, x16);
    twt16_k<<<256, blk, 0, stream>>>(enc_w, enc16, 256, 256, 0);
    twt16_k<<<256, blk, 0, stream>>>(self_w,         l1w, 256, 512, 0);
    twt16_k<<<256, blk, 0, stream>>>(nb_w,           l1w, 256, 512, 256);
    twt16_k<<<256, blk, 0, stream>>>(self_w + 65536, l2w, 256, 512, 0);
    twt16_k<<<256, blk, 0, stream>>>(nb_w + 65536,   l2w, 256, 512, 256);
    twt16_k<<<384, blk, 0, stream>>>(dec_w, dec16, 384, 256, 0);
    twt16_k<<<256, blk, 0, stream>>>(lin_w, lin16, 256, 256, 0);
    bcomb_k<<<2, blk, 0, stream>>>(self_b, nb_b, lbias);
    zero_k<<<64, blk, 0, stream>>>((float*)deg, (size_t)NN);
    hist_k<<<NEDGE / 256, blk, 0, stream>>>(ei, deg);
    scan_k<<<1, 1024, 0, stream>>>(deg, off, cursor);
    fill_k<<<NEDGE / 256, blk, 0, stream>>>(ei, cursor, csr);

    // ---- h0 = gelu(x @ enc_w + enc_b) ----
    mgemm_k<256, 256, false, true, false, false, true><<<dim3(1, 1024), blk, 0, stream>>>(
        x16, nullptr, enc16, enc_b, nullptr, h0);

    // ---- GNN layer 1: h1 = gelu([h0,agg]@W + b) + h0 ----
    gather16_k<<<NN / 4, blk, 0, stream>>>(h0, off, csr, agg);
    mgemm_k<256, 512, true, true, true, false, true><<<dim3(1, 1024), blk, 0, stream>>>(
        h0, agg, l1w, lbias, nullptr, h1);

    // ---- GNN layer 2: h0 = gelu([h1,agg]@W + b) + h1 ----
    gather16_k<<<NN / 4, blk, 0, stream>>>(h1, off, csr, agg);
    mgemm_k<256, 512, true, true, true, false, true><<<dim3(1, 1024), blk, 0, stream>>>(
        h1, agg, l2w, lbias + 256, nullptr, h0);

    // ---- node_rep = h0 @ dec_w + dec_b  (fp16 out; agg+CSR dead) ----
    mgemm_k<384, 256, false, false, false, false, true><<<dim3(1, 1024), dim3(384), 0, stream>>>(
        h0, nullptr, dec16, dec_b, nullptr, nr16);

    // ---- vf1 = Q . x  (x16,h0 dead) ----
    bundle_k<false><<<NN / 4, blk, 0, stream>>>(x, nr16, vf1);

    // ---- spectral filter (scale fused into reproj) ----
    zero_k<<<512, blk, 0, stream>>>(hs, (size_t)GG * KEIG * CH);
    spec_proj_k<<<dim3(GG, 8), blk, 0, stream>>>(vf1, eigvec, hs);
    spec_reproj16_k<<<GG * 16, blk, 0, stream>>>(eigvec, hs, eigval, taus, h2);

    // ---- h3 = h2 @ lin_w + lin_b  (fp32 out; vf1 dead) ----
    mgemm_k<256, 256, false, false, false, true, false><<<dim3(1, 1024), blk, 0, stream>>>(
        h2, nullptr, lin16, lin_b, h3, nullptr);

    // ---- out = Q^T . h3 ----
    bundle_k<true><<<NN / 4, blk, 0, stream>>>(h3, nr16, (float*)d_out);
}

// Round 4
// 845.253 us; speedup vs baseline: 1.0197x; 1.0197x over previous
//
#include <hip/hip_runtime.h>
#include <math.h>

// Problem constants
#define NN      65536
#define GG      64
#define NPG     1024
#define KEIG    32
#define NBUN    64
#define BDIM    4
#define CH      256        // IN_CH == GNN_DIM == NB*BD
#define NBP     384
#define NEDGE   524288

using f16x8 = __attribute__((ext_vector_type(8))) _Float16;
using f16x4 = __attribute__((ext_vector_type(4))) _Float16;
using f32x4 = __attribute__((ext_vector_type(4))) float;

__device__ __forceinline__ float gelu_f(float x) {
    return 0.5f * x * (1.0f + erff(x * 0.70710678118654752440f));
}

// ---------------------------------------------------------------------------
// fp16 MFMA GEMM, LDS-FREE: C = post( A[M,KTOT] @ W ), W as Wt[NOUT,KTOT].
// Evidence so far:
//  R1: global_load_lds DMA staging caps ~1 TB/s regardless of pipelining.
//  R2: direct global->VGPR fragments, waves stacked in M: 2.86 TB/s (unique
//      -miss parallelism works) but 270 MB fetch: the NX sibling n-blocks of
//      one A-panel ran on DIFFERENT XCDs -> no TCC merge -> 4x HBM A-fetch.
//  R3: waves stacked in N (A shared via L1): fetch 84 MB (minimal!) but BW
//      back to 1 TB/s -- same-CU sharing kills unique-miss parallelism.
// R4 = R2 mapping + XCD-aware sibling swizzle: block bid -> xcd = bid&7,
// slot = bid>>3, by = xcd*32 + slot/NX, bx = slot%NX. The NX siblings of an
// A-panel land on the SAME XCD, adjacent in dispatch -> one TCC merges their
// A misses (fetch once globally); per-CU unique-miss parallelism = R2.
// Per-wave: fragment = 16B/lane at (row=lane&15, kchunk=lane>>4) ==
// global_load_dwordx4; 3-stage register pipeline; no LDS, no barriers.
// DUAL: A = concat_k(A1, A2), KTOT=512.
// RESA: + (float)A1[m,n] residual, read-only (requires NOUT==256).
// WF: write fp32 Cf.  W16: write fp16 C16.
// Outputs disjoint from ALL inputs (graph-replay safety).
// ---------------------------------------------------------------------------
template<int NOUT, int KTOT, bool DUAL, bool ACT, bool RESA, bool WF, bool W16>
__global__ __launch_bounds__(256, 2) void mgemm_k(
    const _Float16* __restrict__ A1, const _Float16* __restrict__ A2,
    const _Float16* __restrict__ Wt, const float* __restrict__ bias,
    float* __restrict__ Cf, _Float16* __restrict__ C16)
{
    constexpr int NX = NOUT / 64;      // sibling n-blocks per A-panel
    const int tid  = threadIdx.x;
    const int lane = tid & 63;
    const int wave = tid >> 6;

    // XCD-aware swizzle: keep an A-panel's NX siblings on one XCD.
    const int bid  = blockIdx.x;       // grid = NX * 256 blocks, 1D
    const int xcd  = bid & 7;
    const int slot = bid >> 3;
    const int by   = xcd * 32 + slot / NX;   // A-panel (256 rows)
    const int bx   = slot % NX;              // n-panel (64 cols)

    const int m0   = by * 256 + wave * 64;   // wave's 64 output rows
    const int n0   = bx * 64;                // block's 64 output cols

    const int r16 = lane & 15;   // row (A) / col (B) within 16
    const int kc  = lane >> 4;   // k-chunk 0..3 (8 halfs each)

    // per-thread fragment base pointers (element units); A rows are 256 wide
    const _Float16* a1p = A1 + (size_t)(m0 + r16) * 256 + kc * 8;
    const _Float16* a2p = DUAL ? (A2 + (size_t)(m0 + r16) * 256 + kc * 8) : A1;
    const _Float16* bp  = Wt + (size_t)(n0 + r16) * KTOT + kc * 8;

    constexpr int NT = KTOT / 32;   // 8 or 16 K-steps

    f16x8 af[3][4], bf[3][4];       // 3-stage pipeline, static indices only
    f32x4 acc[4][4];
#pragma unroll
    for (int i = 0; i < 4; i++)
#pragma unroll
        for (int j = 0; j < 4; j++) acc[i][j] = 0.f;

#define LDA(T, S)                                                              \
    {                                                                          \
        const _Float16* ap_ = (DUAL && (T) >= 8) ? (a2p + ((T) - 8) * 32)      \
                                                 : (a1p + (T) * 32);           \
        _Pragma("unroll")                                                      \
        for (int q = 0; q < 4; q++)                                            \
            af[(S)][q] = *(const f16x8*)(ap_ + (size_t)q * 16 * 256);          \
        _Pragma("unroll")                                                      \
        for (int q = 0; q < 4; q++)                                            \
            bf[(S)][q] = *(const f16x8*)(bp + (T) * 32 + (size_t)q * 16 * KTOT); \
    }

    LDA(0, 0)
    LDA(1, 1)
    LDA(2, 2)

#pragma unroll
    for (int t = 0; t < NT; ++t) {
        const int s = t % 3;        // compile-time after full unroll
#pragma unroll
        for (int mt = 0; mt < 4; mt++)
#pragma unroll
            for (int nt = 0; nt < 4; nt++)
                acc[mt][nt] = __builtin_amdgcn_mfma_f32_16x16x32_f16(
                    af[s][mt], bf[s][nt], acc[mt][nt], 0, 0, 0);
        if (t + 3 < NT) LDA(t + 3, s)
    }
#undef LDA

    // epilogue: C[m = quad*4+reg][n = lane&15] per 16x16 tile (m89 layout)
    const int rbase = (lane >> 4) * 4;
    const int ncol  = lane & 15;
#pragma unroll
    for (int nt = 0; nt < 4; nt++) {
        const int n = n0 + nt * 16 + ncol;
        const float bs = bias[n];
#pragma unroll
        for (int mt = 0; mt < 4; mt++) {
#pragma unroll
            for (int i = 0; i < 4; i++) {
                const int m = m0 + mt * 16 + rbase + i;
                const size_t idx = (size_t)m * NOUT + n;
                float v = acc[mt][nt][i] + bs;
                if (ACT) v = gelu_f(v);
                if (RESA) v += (float)A1[(size_t)m * 256 + n];
                if (WF) Cf[idx] = v;
                if (W16) C16[idx] = (_Float16)v;
            }
        }
    }
}

// ---------------------------------------------------------------------------
__global__ void zero_k(float* __restrict__ p, size_t n)
{
    size_t i = (size_t)blockIdx.x * blockDim.x + threadIdx.x;
    float4* p4 = (float4*)p;
    size_t n4 = n >> 2;
    for (size_t j = i; j < n4; j += (size_t)gridDim.x * blockDim.x)
        p4[j] = make_float4(0.f, 0.f, 0.f, 0.f);
}

// fp32 -> fp16 convert (4 elems/thread)
__global__ __launch_bounds__(256) void cvt16_k(
    const float* __restrict__ in, _Float16* __restrict__ out)
{
    size_t i = (size_t)blockIdx.x * 256 + threadIdx.x;
    float4 v = ((const float4*)in)[i];
    f16x4 o = { (_Float16)v.x, (_Float16)v.y, (_Float16)v.z, (_Float16)v.w };
    ((f16x4*)out)[i] = o;
}

// weight transpose+convert: Wt[n*ldw + koff + k] = f16(W[k*N + n]); K=256
__global__ __launch_bounds__(256) void twt16_k(
    const float* __restrict__ W, _Float16* __restrict__ Wt,
    int N, int ldw, int koff)
{
    int i = blockIdx.x * 256 + threadIdx.x;   // over 256*N
    int k = i & 255, n = i >> 8;
    if (n < N) Wt[(size_t)n * ldw + koff + k] = (_Float16)W[(size_t)k * N + n];
}

__global__ void bcomb_k(const float* __restrict__ a, const float* __restrict__ b,
                        float* __restrict__ o)
{
    int i = blockIdx.x * 256 + threadIdx.x;
    if (i < 512) o[i] = a[i] + b[i];
}

// ---------------------------------------------------------------------------
// CSR build: histogram of dst, exclusive scan, cursor fill
// ---------------------------------------------------------------------------
__global__ __launch_bounds__(256) void hist_k(const int* __restrict__ ei, int* __restrict__ deg)
{
    int e = blockIdx.x * 256 + threadIdx.x;
    if (e < NEDGE) atomicAdd(&deg[ei[NEDGE + e]], 1);
}

__global__ __launch_bounds__(1024) void scan_k(
    const int* __restrict__ deg, int* __restrict__ off, int* __restrict__ cursor)
{
    __shared__ int sh[1024];
    const int tid = threadIdx.x;
    const int base = tid * 64;
    int s = 0;
#pragma unroll 8
    for (int i = 0; i < 64; i++) s += deg[base + i];
    const int mysum = s;
    sh[tid] = s;
    __syncthreads();
    for (int ofs = 1; ofs < 1024; ofs <<= 1) {
        int v = (tid >= ofs) ? sh[tid - ofs] : 0;
        __syncthreads();
        sh[tid] += v;
        __syncthreads();
    }
    int running = sh[tid] - mysum;
    for (int i = 0; i < 64; i++) {
        off[base + i] = running;
        cursor[base + i] = running;
        running += deg[base + i];
    }
    if (tid == 1023) off[NN] = running;
}

__global__ __launch_bounds__(256) void fill_k(
    const int* __restrict__ ei, int* __restrict__ cursor, int* __restrict__ csr)
{
    int e = blockIdx.x * 256 + threadIdx.x;
    if (e < NEDGE) {
        int d = ei[NEDGE + e];
        int pos = atomicAdd(&cursor[d], 1);
        csr[pos] = ei[e];   // src
    }
}

// ---------------------------------------------------------------------------
// Gather segment-sum over fp16 h: fp32 accum, fp16 out
// ---------------------------------------------------------------------------
__global__ __launch_bounds__(256) void gather16_k(
    const _Float16* __restrict__ h, const int* __restrict__ off,
    const int* __restrict__ csr, _Float16* __restrict__ agg)
{
    const int lane = threadIdx.x & 63;
    const int n = blockIdx.x * 4 + (threadIdx.x >> 6);
    const int s0 = off[n], s1 = off[n + 1];
    float a0 = 0.f, a1 = 0.f, a2 = 0.f, a3 = 0.f;
    int j = s0;
    for (; j + 1 < s1; j += 2) {
        f16x4 va = ((const f16x4*)(h + (size_t)csr[j] * CH))[lane];
        f16x4 vb = ((const f16x4*)(h + (size_t)csr[j + 1] * CH))[lane];
        a0 += (float)va[0] + (float)vb[0]; a1 += (float)va[1] + (float)vb[1];
        a2 += (float)va[2] + (float)vb[2]; a3 += (float)va[3] + (float)vb[3];
    }
    if (j < s1) {
        f16x4 va = ((const f16x4*)(h + (size_t)csr[j] * CH))[lane];
        a0 += (float)va[0]; a1 += (float)va[1]; a2 += (float)va[2]; a3 += (float)va[3];
    }
    f16x4 o = { (_Float16)a0, (_Float16)a1, (_Float16)a2, (_Float16)a3 };
    ((f16x4*)(agg + (size_t)n * CH))[lane] = o;
}

// ---------------------------------------------------------------------------
// Householder Q from 6 fp16 params (BD=4: 3 reflectors)
// ---------------------------------------------------------------------------
__device__ __forceinline__ void make_Q(const _Float16* __restrict__ p, float Q[4][4])
{
#pragma unroll
    for (int i = 0; i < 4; i++)
#pragma unroll
        for (int j = 0; j < 4; j++) Q[i][j] = (i == j) ? 1.f : 0.f;
    int idx = 0;
#pragma unroll
    for (int j = 0; j < 3; j++) {
        float v[4] = {0.f, 0.f, 0.f, 0.f};
        v[j] = 1.f;
#pragma unroll
        for (int t = 0; t < 4; t++)
            if (t > j) v[t] = (float)p[idx + t - (j + 1)];
        idx += 3 - j;
        float nrm = v[0]*v[0] + v[1]*v[1] + v[2]*v[2] + v[3]*v[3];
        float s = 2.f / nrm;
#pragma unroll
        for (int i = 0; i < 4; i++) {
            float qv = Q[i][0]*v[0] + Q[i][1]*v[1] + Q[i][2]*v[2] + Q[i][3]*v[3];
            float t0 = s * qv;
#pragma unroll
            for (int c = 0; c < 4; c++) Q[i][c] -= t0 * v[c];
        }
    }
}

// Bundle transform: block = 4 nodes x 64 bundles; node_rep is fp16
template<bool TRANS>
__global__ __launch_bounds__(256) void bundle_k(
    const float* __restrict__ vin, const _Float16* __restrict__ nr,
    float* __restrict__ out)
{
    __shared__ _Float16 pb[4 * NBP];
    const int n0 = blockIdx.x * 4;
    for (int i = threadIdx.x; i < 4 * NBP; i += 256)
        pb[i] = nr[(size_t)n0 * NBP + i];
    __syncthreads();
    const int ln = threadIdx.x >> 6;
    const int b  = threadIdx.x & 63;
    const int n  = n0 + ln;
    float Q[4][4];
    make_Q(&pb[ln * NBP + b * 6], Q);
    float4 xv = ((const float4*)(vin + (size_t)n * CH))[b];
    float in0 = xv.x, in1 = xv.y, in2 = xv.z, in3 = xv.w;
    float4 o;
    if constexpr (!TRANS) {
        o.x = Q[0][0]*in0 + Q[0][1]*in1 + Q[0][2]*in2 + Q[0][3]*in3;
        o.y = Q[1][0]*in0 + Q[1][1]*in1 + Q[1][2]*in2 + Q[1][3]*in3;
        o.z = Q[2][0]*in0 + Q[2][1]*in1 + Q[2][2]*in2 + Q[2][3]*in3;
        o.w = Q[3][0]*in0 + Q[3][1]*in1 + Q[3][2]*in2 + Q[3][3]*in3;
    } else {
        o.x = Q[0][0]*in0 + Q[1][0]*in1 + Q[2][0]*in2 + Q[3][0]*in3;
        o.y = Q[0][1]*in0 + Q[1][1]*in1 + Q[2][1]*in2 + Q[3][1]*in3;
        o.z = Q[0][2]*in0 + Q[1][2]*in1 + Q[2][2]*in2 + Q[3][2]*in3;
        o.w = Q[0][3]*in0 + Q[1][3]*in1 + Q[2][3]*in2 + Q[3][3]*in3;
    }
    ((float4*)(out + (size_t)n * CH))[b] = o;
}

// ---------------------------------------------------------------------------
// Spectral kernels
// ---------------------------------------------------------------------------
__global__ __launch_bounds__(256) void spec_proj_k(
    const float* __restrict__ v, const float* __restrict__ eigvec, float* __restrict__ hs)
{
    const int g = blockIdx.x;
    const int nbase = g * NPG + blockIdx.y * 128;
    __shared__ float evs[16][32];
    float acc[32];
#pragma unroll
    for (int k = 0; k < 32; k++) acc[k] = 0.f;
    for (int nt = 0; nt < 128; nt += 16) {
        __syncthreads();
        for (int i = threadIdx.x; i < 512; i += 256) {
            int nn = i >> 5, kk = i & 31;
            evs[nn][kk] = eigvec[(size_t)(nbase + nt + nn) * KEIG + kk];
        }
        __syncthreads();
#pragma unroll 4
        for (int nn = 0; nn < 16; nn++) {
            float hv = v[(size_t)(nbase + nt + nn) * CH + threadIdx.x];
#pragma unroll
            for (int k = 0; k < 32; k++) acc[k] += evs[nn][k] * hv;
        }
    }
    float* o = hs + (size_t)g * KEIG * CH + threadIdx.x;
#pragma unroll
    for (int k = 0; k < 32; k++) atomicAdd(o + k * CH, acc[k]);
}

// out16[g,n,d] = sum_v ev[g,n,v] * hs[g,v,d] * exp(-eigval[g,v]*taus[d>>2])
// (spec_scale fused into the hs load)
__global__ __launch_bounds__(256) void spec_reproj16_k(
    const float* __restrict__ eigvec, const float* __restrict__ hs,
    const float* __restrict__ eigval, const float* __restrict__ taus,
    _Float16* __restrict__ out16)
{
    const int g = blockIdx.x >> 4;
    const int nbase = g * NPG + (blockIdx.x & 15) * 64;
    const float tau = taus[threadIdx.x >> 2];
    float hsr[32];
    const float* hg = hs + (size_t)g * KEIG * CH + threadIdx.x;
#pragma unroll
    for (int k = 0; k < 32; k++)
        hsr[k] = hg[k * CH] * expf(-eigval[g * KEIG + k] * tau);
    __shared__ float evs[64][32];
    for (int i = threadIdx.x; i < 2048; i += 256) {
        int nn = i >> 5, kk = i & 31;
        evs[nn][kk] = eigvec[(size_t)(nbase + nn) * KEIG + kk];
    }
    __syncthreads();
    for (int nn = 0; nn < 64; nn++) {
        float a = 0.f;
#pragma unroll
        for (int k = 0; k < 32; k++) a += evs[nn][k] * hsr[k];
        out16[(size_t)(nbase + nn) * CH + threadIdx.x] = (_Float16)a;
    }
}

// ---------------------------------------------------------------------------
extern "C" void kernel_launch(void* const* d_in, const int* in_sizes, int n_in,
                              void* d_out, int out_size, void* d_ws, size_t ws_size,
                              hipStream_t stream)
{
    const float* x      = (const float*)d_in[0];
    const float* eigvec = (const float*)d_in[1];
    const float* eigval = (const float*)d_in[2];
    const float* taus   = (const float*)d_in[3];
    const float* enc_w  = (const float*)d_in[4];
    const float* enc_b  = (const float*)d_in[5];
    const float* self_w = (const float*)d_in[6];
    const float* self_b = (const float*)d_in[7];
    const float* nb_w   = (const float*)d_in[8];
    const float* nb_b   = (const float*)d_in[9];
    const float* dec_w  = (const float*)d_in[10];
    const float* dec_b  = (const float*)d_in[11];
    const float* lin_w  = (const float*)d_in[12];
    const float* lin_b  = (const float*)d_in[13];
    const int*   ei     = (const int*)d_in[14];
    (void)in_sizes; (void)n_in; (void)out_size; (void)ws_size;

    float* ws = (float*)d_ws;
    // fp16 [NN,256] plane = 16,777,216 halfs = 8,388,608 FLOAT-SLOTS (round-6
    // bug: was sized 4,194,304 -> agg stomped CSR -> wild gathers -> fault).
    // Stream-ordered lifetimes (float-slot offsets):
    //  [0,        8388608)  x16          -> vf1[0:half] / h3
    //  [8388608, 16777216)  h0           -> vf1[half:]  / h3
    //  [16777216,25165824)  h1           -> hs (@16.7M) ; free tail
    //  [25165824,33554432)  agg          -> nr16 part
    //  [33554432,34275329)  CSR ints     -> nr16 part
    //  [25165824,37748736)  nr16 [NN,384] fp16 (dec out; agg+CSR dead)
    //  [37748752,37995024)  weights + lbias
    //  [37995024,46383632)  h2 [NN,256] fp16
    // high-water: 46,383,632 fl = 185.5 MB
    _Float16* x16 = (_Float16*)(ws);
    _Float16* h0  = (_Float16*)(ws + 8388608);
    _Float16* h1  = (_Float16*)(ws + 16777216);
    _Float16* agg = (_Float16*)(ws + 25165824);
    int* ibase  = (int*)(ws + 33554432);
    int* deg    = ibase;                 // NN
    int* off    = ibase + 65536;         // NN+1
    int* cursor = ibase + 131073;        // NN
    int* csr    = ibase + 196609;        // NEDGE (ends slot 34275329)
    _Float16* nr16 = (_Float16*)(ws + 25165824);  // [NN,384] fp16
    float* wb = ws + 37748752;
    _Float16* enc16 = (_Float16*)(wb);            // [256,256]
    _Float16* l1w   = (_Float16*)(wb + 32768);    // [256,512]
    _Float16* l2w   = (_Float16*)(wb + 98304);    // [256,512]
    _Float16* dec16 = (_Float16*)(wb + 163840);   // [384,256]
    _Float16* lin16 = (_Float16*)(wb + 212992);   // [256,256]
    float* lbias = wb + 245760;                   // [2,256] (ends wb+246272)
    _Float16* h2 = (_Float16*)(ws + 37995024);    // [NN,256] fp16
    float* vf1 = ws;                              // [NN,256] fp32 (x16,h0 dead)
    float* hs  = ws + 16777216;                   // [64,32,256] fp32 (h1 dead)
    float* h3  = vf1;                             // vf1 dead after spec_proj

    dim3 blk(256);

    // ---- prep ----
    cvt16_k<<<16384, blk, 0, stream>>>(x, x16);
    twt16_k<<<256, blk, 0, stream>>>(enc_w, enc16, 256, 256, 0);
    twt16_k<<<256, blk, 0, stream>>>(self_w,         l1w, 256, 512, 0);
    twt16_k<<<256, blk, 0, stream>>>(nb_w,           l1w, 256, 512, 256);
    twt16_k<<<256, blk, 0, stream>>>(self_w + 65536, l2w, 256, 512, 0);
    twt16_k<<<256, blk, 0, stream>>>(nb_w + 65536,   l2w, 256, 512, 256);
    twt16_k<<<384, blk, 0, stream>>>(dec_w, dec16, 384, 256, 0);
    twt16_k<<<256, blk, 0, stream>>>(lin_w, lin16, 256, 256, 0);
    bcomb_k<<<2, blk, 0, stream>>>(self_b, nb_b, lbias);
    zero_k<<<64, blk, 0, stream>>>((float*)deg, (size_t)NN);
    hist_k<<<NEDGE / 256, blk, 0, stream>>>(ei, deg);
    scan_k<<<1, 1024, 0, stream>>>(deg, off, cursor);
    fill_k<<<NEDGE / 256, blk, 0, stream>>>(ei, cursor, csr);

    // ---- h0 = gelu(x @ enc_w + enc_b) ----
    mgemm_k<256, 256, false, true, false, false, true><<<dim3(1024), blk, 0, stream>>>(
        x16, nullptr, enc16, enc_b, nullptr, h0);

    // ---- GNN layer 1: h1 = gelu([h0,agg]@W + b) + h0 ----
    gather16_k<<<NN / 4, blk, 0, stream>>>(h0, off, csr, agg);
    mgemm_k<256, 512, true, true, true, false, true><<<dim3(1024), blk, 0, stream>>>(
        h0, agg, l1w, lbias, nullptr, h1);

    // ---- GNN layer 2: h0 = gelu([h1,agg]@W + b) + h1 ----
    gather16_k<<<NN / 4, blk, 0, stream>>>(h1, off, csr, agg);
    mgemm_k<256, 512, true, true, true, false, true><<<dim3(1024), blk, 0, stream>>>(
        h1, agg, l2w, lbias + 256, nullptr, h0);

    // ---- node_rep = h0 @ dec_w + dec_b  (fp16 out; agg+CSR dead) ----
    mgemm_k<384, 256, false, false, false, false, true><<<dim3(1536), blk, 0, stream>>>(
        h0, nullptr, dec16, dec_b, nullptr, nr16);

    // ---- vf1 = Q . x  (x16,h0 dead) ----
    bundle_k<false><<<NN / 4, blk, 0, stream>>>(x, nr16, vf1);

    // ---- spectral filter (scale fused into reproj) ----
    zero_k<<<512, blk, 0, stream>>>(hs, (size_t)GG * KEIG * CH);
    spec_proj_k<<<dim3(GG, 8), blk, 0, stream>>>(vf1, eigvec, hs);
    spec_reproj16_k<<<GG * 16, blk, 0, stream>>>(eigvec, hs, eigval, taus, h2);

    // ---- h3 = h2 @ lin_w + lin_b  (fp32 out; vf1 dead) ----
    mgemm_k<256, 256, false, false, false, true, false><<<dim3(1024), blk, 0, stream>>>(
        h2, nullptr, lin16, lin_b, h3, nullptr);

    // ---- out = Q^T . h3 ----
    bundle_k<true><<<NN / 4, blk, 0, stream>>>(h3, nr16, (float*)d_out);
}

// Round 5
// 711.472 us; speedup vs baseline: 1.2114x; 1.1880x over previous
//
#include <hip/hip_runtime.h>
#include <math.h>

// Problem constants
#define NN      65536
#define GG      64
#define NPG     1024
#define KEIG    32
#define NBUN    64
#define BDIM    4
#define CH      256        // IN_CH == GNN_DIM == NB*BD
#define NBP     384
#define NEDGE   524288

using f16x8 = __attribute__((ext_vector_type(8))) _Float16;
using f16x4 = __attribute__((ext_vector_type(4))) _Float16;
using f32x4 = __attribute__((ext_vector_type(4))) float;

__device__ __forceinline__ float gelu_f(float x) {
    return 0.5f * x * (1.0f + erff(x * 0.70710678118654752440f));
}

// ---------------------------------------------------------------------------
// fp16 MFMA GEMM. Evidence through R4: dispatch time ~110us INVARIANT across
// staging schemes (GLL 1TB/s cap; direct-fragment loads 2.9TB/s but same dur;
// traffic 80-270MB; swizzle fixed fetch not time). Common factor: every load
// instruction scattered 64 lanes over 16 distinct 64B segments (fragment rows
// at 512B stride) -> address/TA throughput bound, instruction-count invariant.
// R5: every global load is 1KB CONTIGUOUS.
//  - A: full-K panel (64 rows x KTOT) staged ONCE per block into LDS via
//    register-pipelined dwordx4 (full rows are contiguous); ONE barrier;
//    K-loop reads fragments with XOR-swizzled ds_read_b128 (full-offset XOR,
//    same involution on write+read; (row&7)<<4 -> 2 lanes/bank = free).
//  - B: weights PRE-PACKED into fragment order (pack_k) so each B-fragment
//    load inst is lane-contiguous 1KB; pipelined 2 K-steps ahead in NAMED
//    register sets (no runtime-indexed arrays -> no scratch).
//  - Waves stack in N (wave wn owns cols wn*64..): A shared via LDS, fetched
//    once globally; B tiny (<=512KB), L2-resident.
// DUAL: A = concat_k(A1, A2), KTOT=512.
// RESA: + (float)A1[m,n] residual (requires NOUT==256).
// WF: write fp32 Cf.  W16: write fp16 C16.
// Outputs disjoint from ALL inputs (graph-replay safety).
// ---------------------------------------------------------------------------
template<int NOUT, int KTOT, bool DUAL, bool ACT, bool RESA, bool WF, bool W16>
__global__ __launch_bounds__(NOUT, 2) void mgemm_k(
    const _Float16* __restrict__ A1, const _Float16* __restrict__ A2,
    const _Float16* __restrict__ Bp, const float* __restrict__ bias,
    float* __restrict__ Cf, _Float16* __restrict__ C16)
{
    constexpr int NT   = KTOT / 32;     // K-steps
    constexpr int ROWB = KTOT * 2;      // LDS bytes per A row
    constexpr int CPR  = KTOT / 8;      // 16B chunks per A row
    __shared__ _Float16 Alds[64 * KTOT];   // 32 KB (K=256) / 64 KB (K=512)

    const int tid  = threadIdx.x;
    const int lane = tid & 63;
    const int wave = tid >> 6;          // wave owns cols wave*64..wave*64+63
    const int m0   = blockIdx.x * 64;   // block's 64 A rows

    // ---- stage full A panel once: coalesced loads -> regs -> swizzled LDS --
    constexpr int TOTC = 64 * CPR;
    constexpr int NSTG = TOTC / NOUT;   // full iters per thread
    {
        f16x8 stg[NSTG ? NSTG : 1];
#pragma unroll
        for (int j = 0; j < NSTG; j++) {
            const int idx = tid + j * NOUT;
            const int r = idx / CPR, c = idx - r * CPR;
            const _Float16* src = (DUAL && c >= CPR / 2)
                ? A2 + (size_t)(m0 + r) * 256 + (c - CPR / 2) * 8
                : A1 + (size_t)(m0 + r) * 256 + c * 8;
            stg[j] = *(const f16x8*)src;
        }
#pragma unroll
        for (int j = 0; j < NSTG; j++) {
            const int idx = tid + j * NOUT;
            const int r = idx / CPR, c = idx - r * CPR;
            *(f16x8*)((char*)Alds + ((r * ROWB + c * 16) ^ ((r & 7) << 4))) = stg[j];
        }
        if (TOTC % NOUT) {              // remainder (NOUT=384 case)
            const int idx = tid + NSTG * NOUT;
            if (idx < TOTC) {
                const int r = idx / CPR, c = idx - r * CPR;
                const _Float16* src = (DUAL && c >= CPR / 2)
                    ? A2 + (size_t)(m0 + r) * 256 + (c - CPR / 2) * 8
                    : A1 + (size_t)(m0 + r) * 256 + c * 8;
                f16x8 v = *(const f16x8*)src;
                *(f16x8*)((char*)Alds + ((r * ROWB + c * 16) ^ ((r & 7) << 4))) = v;
            }
        }
    }
    __syncthreads();                    // only barrier in the kernel

    const int r16 = lane & 15;          // fragment row / col within 16
    const int kc  = lane >> 4;          // k-chunk 0..3

    // B packed: chunk((wn*NT + t)*4 + q), lane-contiguous 16B each
    const _Float16* bpp = Bp + ((size_t)wave * NT * 2048) + lane * 8;

    f32x4 acc[4][4];
#pragma unroll
    for (int i = 0; i < 4; i++)
#pragma unroll
        for (int j = 0; j < 4; j++) acc[i][j] = 0.f;

    f16x8 p00, p01, p02, p03, p10, p11, p12, p13;

#define LDB(P0, P1, P2, P3, T)                                                 \
    {                                                                          \
        const _Float16* bq_ = bpp + (size_t)(T) * 2048;                        \
        P0 = *(const f16x8*)(bq_);                                             \
        P1 = *(const f16x8*)(bq_ + 512);                                       \
        P2 = *(const f16x8*)(bq_ + 1024);                                      \
        P3 = *(const f16x8*)(bq_ + 1536);                                      \
    }

#define MSTEP(OFF, P0, P1, P2, P3)                                             \
    {                                                                          \
        const char* ap_ = (const char*)Alds + (OFF);                           \
        f16x8 a0_ = *(const f16x8*)(ap_);                                      \
        f16x8 a1_ = *(const f16x8*)(ap_ + 16 * ROWB);                          \
        f16x8 a2_ = *(const f16x8*)(ap_ + 32 * ROWB);                          \
        f16x8 a3_ = *(const f16x8*)(ap_ + 48 * ROWB);                          \
        acc[0][0] = __builtin_amdgcn_mfma_f32_16x16x32_f16(a0_, P0, acc[0][0], 0, 0, 0); \
        acc[0][1] = __builtin_amdgcn_mfma_f32_16x16x32_f16(a0_, P1, acc[0][1], 0, 0, 0); \
        acc[0][2] = __builtin_amdgcn_mfma_f32_16x16x32_f16(a0_, P2, acc[0][2], 0, 0, 0); \
        acc[0][3] = __builtin_amdgcn_mfma_f32_16x16x32_f16(a0_, P3, acc[0][3], 0, 0, 0); \
        acc[1][0] = __builtin_amdgcn_mfma_f32_16x16x32_f16(a1_, P0, acc[1][0], 0, 0, 0); \
        acc[1][1] = __builtin_amdgcn_mfma_f32_16x16x32_f16(a1_, P1, acc[1][1], 0, 0, 0); \
        acc[1][2] = __builtin_amdgcn_mfma_f32_16x16x32_f16(a1_, P2, acc[1][2], 0, 0, 0); \
        acc[1][3] = __builtin_amdgcn_mfma_f32_16x16x32_f16(a1_, P3, acc[1][3], 0, 0, 0); \
        acc[2][0] = __builtin_amdgcn_mfma_f32_16x16x32_f16(a2_, P0, acc[2][0], 0, 0, 0); \
        acc[2][1] = __builtin_amdgcn_mfma_f32_16x16x32_f16(a2_, P1, acc[2][1], 0, 0, 0); \
        acc[2][2] = __builtin_amdgcn_mfma_f32_16x16x32_f16(a2_, P2, acc[2][2], 0, 0, 0); \
        acc[2][3] = __builtin_amdgcn_mfma_f32_16x16x32_f16(a2_, P3, acc[2][3], 0, 0, 0); \
        acc[3][0] = __builtin_amdgcn_mfma_f32_16x16x32_f16(a3_, P0, acc[3][0], 0, 0, 0); \
        acc[3][1] = __builtin_amdgcn_mfma_f32_16x16x32_f16(a3_, P1, acc[3][1], 0, 0, 0); \
        acc[3][2] = __builtin_amdgcn_mfma_f32_16x16x32_f16(a3_, P2, acc[3][2], 0, 0, 0); \
        acc[3][3] = __builtin_amdgcn_mfma_f32_16x16x32_f16(a3_, P3, acc[3][3], 0, 0, 0); \
    }

    LDB(p00, p01, p02, p03, 0)
    LDB(p10, p11, p12, p13, 1)

    int au = r16 * ROWB + kc * 16;      // unswizzled byte offset, step 0
    const int swz = (r16 & 7) << 4;
    for (int t = 0; t < NT; t += 2) {
        MSTEP(au ^ swz, p00, p01, p02, p03)
        if (t + 2 < NT) LDB(p00, p01, p02, p03, t + 2)
        MSTEP((au + 64) ^ swz, p10, p11, p12, p13)
        if (t + 3 < NT) LDB(p10, p11, p12, p13, t + 3)
        au += 128;
    }
#undef LDB
#undef MSTEP

    // epilogue: C[m = quad*4+reg][n = lane&15] per 16x16 tile (m89 layout)
    const int rbase = (lane >> 4) * 4;
    const int ncol  = lane & 15;
#pragma unroll
    for (int nt = 0; nt < 4; nt++) {
        const int n = wave * 64 + nt * 16 + ncol;
        const float bs = bias[n];
#pragma unroll
        for (int mt = 0; mt < 4; mt++) {
#pragma unroll
            for (int i = 0; i < 4; i++) {
                const int m = m0 + mt * 16 + rbase + i;
                const size_t idx = (size_t)m * NOUT + n;
                float v = acc[mt][nt][i] + bs;
                if (ACT) v = gelu_f(v);
                if (RESA) v += (float)A1[(size_t)m * 256 + n];
                if (WF) Cf[idx] = v;
                if (W16) C16[idx] = (_Float16)v;
            }
        }
    }
}

// ---------------------------------------------------------------------------
// Weight pack: fp32 W[k][n] (k-major, row stride NOUT) -> fragment-ordered
// fp16 chunks. Chunk cid = ((wn*NT + t)*4 + q)*64 + l holds 8 halfs:
// value[j] = W[t*32 + (l>>4)*8 + j][wn*64 + q*16 + (l&15)].
// DUAL: k >= 256 reads W2[k-256][n].
// ---------------------------------------------------------------------------
template<int NOUT, int KTOT, bool DUAL>
__global__ __launch_bounds__(256) void pack_k(
    const float* __restrict__ W1, const float* __restrict__ W2,
    _Float16* __restrict__ Bp)
{
    constexpr int NT = KTOT / 32;
    const int cid = blockIdx.x * 256 + threadIdx.x;
    if (cid >= NOUT * KTOT / 8) return;
    const int l  = cid & 63;
    const int q  = (cid >> 6) & 3;
    const int c2 = cid >> 8;            // wn*NT + t
    const int t  = c2 & (NT - 1);
    const int wn = c2 / NT;
    const int n  = wn * 64 + q * 16 + (l & 15);
    const int k0 = t * 32 + (l >> 4) * 8;
    f16x8 v;
#pragma unroll
    for (int j = 0; j < 8; j++) {
        const int k = k0 + j;
        float w = (DUAL && k >= 256) ? W2[(size_t)(k - 256) * NOUT + n]
                                     : W1[(size_t)k * NOUT + n];
        v[j] = (_Float16)w;
    }
    *(f16x8*)(Bp + (size_t)cid * 8) = v;
}

// ---------------------------------------------------------------------------
__global__ void zero_k(float* __restrict__ p, size_t n)
{
    size_t i = (size_t)blockIdx.x * blockDim.x + threadIdx.x;
    float4* p4 = (float4*)p;
    size_t n4 = n >> 2;
    for (size_t j = i; j < n4; j += (size_t)gridDim.x * blockDim.x)
        p4[j] = make_float4(0.f, 0.f, 0.f, 0.f);
}

// fp32 -> fp16 convert (4 elems/thread)
__global__ __launch_bounds__(256) void cvt16_k(
    const float* __restrict__ in, _Float16* __restrict__ out)
{
    size_t i = (size_t)blockIdx.x * 256 + threadIdx.x;
    float4 v = ((const float4*)in)[i];
    f16x4 o = { (_Float16)v.x, (_Float16)v.y, (_Float16)v.z, (_Float16)v.w };
    ((f16x4*)out)[i] = o;
}

__global__ void bcomb_k(const float* __restrict__ a, const float* __restrict__ b,
                        float* __restrict__ o)
{
    int i = blockIdx.x * 256 + threadIdx.x;
    if (i < 512) o[i] = a[i] + b[i];
}

// ---------------------------------------------------------------------------
// CSR build: histogram of dst, exclusive scan, cursor fill
// ---------------------------------------------------------------------------
__global__ __launch_bounds__(256) void hist_k(const int* __restrict__ ei, int* __restrict__ deg)
{
    int e = blockIdx.x * 256 + threadIdx.x;
    if (e < NEDGE) atomicAdd(&deg[ei[NEDGE + e]], 1);
}

__global__ __launch_bounds__(1024) void scan_k(
    const int* __restrict__ deg, int* __restrict__ off, int* __restrict__ cursor)
{
    __shared__ int sh[1024];
    const int tid = threadIdx.x;
    const int base = tid * 64;
    int s = 0;
#pragma unroll 8
    for (int i = 0; i < 64; i++) s += deg[base + i];
    const int mysum = s;
    sh[tid] = s;
    __syncthreads();
    for (int ofs = 1; ofs < 1024; ofs <<= 1) {
        int v = (tid >= ofs) ? sh[tid - ofs] : 0;
        __syncthreads();
        sh[tid] += v;
        __syncthreads();
    }
    int running = sh[tid] - mysum;
    for (int i = 0; i < 64; i++) {
        off[base + i] = running;
        cursor[base + i] = running;
        running += deg[base + i];
    }
    if (tid == 1023) off[NN] = running;
}

__global__ __launch_bounds__(256) void fill_k(
    const int* __restrict__ ei, int* __restrict__ cursor, int* __restrict__ csr)
{
    int e = blockIdx.x * 256 + threadIdx.x;
    if (e < NEDGE) {
        int d = ei[NEDGE + e];
        int pos = atomicAdd(&cursor[d], 1);
        csr[pos] = ei[e];   // src
    }
}

// ---------------------------------------------------------------------------
// Gather segment-sum over fp16 h: fp32 accum, fp16 out
// ---------------------------------------------------------------------------
__global__ __launch_bounds__(256) void gather16_k(
    const _Float16* __restrict__ h, const int* __restrict__ off,
    const int* __restrict__ csr, _Float16* __restrict__ agg)
{
    const int lane = threadIdx.x & 63;
    const int n = blockIdx.x * 4 + (threadIdx.x >> 6);
    const int s0 = off[n], s1 = off[n + 1];
    float a0 = 0.f, a1 = 0.f, a2 = 0.f, a3 = 0.f;
    int j = s0;
    for (; j + 1 < s1; j += 2) {
        f16x4 va = ((const f16x4*)(h + (size_t)csr[j] * CH))[lane];
        f16x4 vb = ((const f16x4*)(h + (size_t)csr[j + 1] * CH))[lane];
        a0 += (float)va[0] + (float)vb[0]; a1 += (float)va[1] + (float)vb[1];
        a2 += (float)va[2] + (float)vb[2]; a3 += (float)va[3] + (float)vb[3];
    }
    if (j < s1) {
        f16x4 va = ((const f16x4*)(h + (size_t)csr[j] * CH))[lane];
        a0 += (float)va[0]; a1 += (float)va[1]; a2 += (float)va[2]; a3 += (float)va[3];
    }
    f16x4 o = { (_Float16)a0, (_Float16)a1, (_Float16)a2, (_Float16)a3 };
    ((f16x4*)(agg + (size_t)n * CH))[lane] = o;
}

// ---------------------------------------------------------------------------
// Householder Q from 6 fp16 params (BD=4: 3 reflectors)
// ---------------------------------------------------------------------------
__device__ __forceinline__ void make_Q(const _Float16* __restrict__ p, float Q[4][4])
{
#pragma unroll
    for (int i = 0; i < 4; i++)
#pragma unroll
        for (int j = 0; j < 4; j++) Q[i][j] = (i == j) ? 1.f : 0.f;
    int idx = 0;
#pragma unroll
    for (int j = 0; j < 3; j++) {
        float v[4] = {0.f, 0.f, 0.f, 0.f};
        v[j] = 1.f;
#pragma unroll
        for (int t = 0; t < 4; t++)
            if (t > j) v[t] = (float)p[idx + t - (j + 1)];
        idx += 3 - j;
        float nrm = v[0]*v[0] + v[1]*v[1] + v[2]*v[2] + v[3]*v[3];
        float s = 2.f / nrm;
#pragma unroll
        for (int i = 0; i < 4; i++) {
            float qv = Q[i][0]*v[0] + Q[i][1]*v[1] + Q[i][2]*v[2] + Q[i][3]*v[3];
            float t0 = s * qv;
#pragma unroll
            for (int c = 0; c < 4; c++) Q[i][c] -= t0 * v[c];
        }
    }
}

// Bundle transform: block = 4 nodes x 64 bundles; node_rep is fp16
template<bool TRANS>
__global__ __launch_bounds__(256) void bundle_k(
    const float* __restrict__ vin, const _Float16* __restrict__ nr,
    float* __restrict__ out)
{
    __shared__ _Float16 pb[4 * NBP];
    const int n0 = blockIdx.x * 4;
    for (int i = threadIdx.x; i < 4 * NBP; i += 256)
        pb[i] = nr[(size_t)n0 * NBP + i];
    __syncthreads();
    const int ln = threadIdx.x >> 6;
    const int b  = threadIdx.x & 63;
    const int n  = n0 + ln;
    float Q[4][4];
    make_Q(&pb[ln * NBP + b * 6], Q);
    float4 xv = ((const float4*)(vin + (size_t)n * CH))[b];
    float in0 = xv.x, in1 = xv.y, in2 = xv.z, in3 = xv.w;
    float4 o;
    if constexpr (!TRANS) {
        o.x = Q[0][0]*in0 + Q[0][1]*in1 + Q[0][2]*in2 + Q[0][3]*in3;
        o.y = Q[1][0]*in0 + Q[1][1]*in1 + Q[1][2]*in2 + Q[1][3]*in3;
        o.z = Q[2][0]*in0 + Q[2][1]*in1 + Q[2][2]*in2 + Q[2][3]*in3;
        o.w = Q[3][0]*in0 + Q[3][1]*in1 + Q[3][2]*in2 + Q[3][3]*in3;
    } else {
        o.x = Q[0][0]*in0 + Q[1][0]*in1 + Q[2][0]*in2 + Q[3][0]*in3;
        o.y = Q[0][1]*in0 + Q[1][1]*in1 + Q[2][1]*in2 + Q[3][1]*in3;
        o.z = Q[0][2]*in0 + Q[1][2]*in1 + Q[2][2]*in2 + Q[3][2]*in3;
        o.w = Q[0][3]*in0 + Q[1][3]*in1 + Q[2][3]*in2 + Q[3][3]*in3;
    }
    ((float4*)(out + (size_t)n * CH))[b] = o;
}

// ---------------------------------------------------------------------------
// Spectral kernels
// ---------------------------------------------------------------------------
__global__ __launch_bounds__(256) void spec_proj_k(
    const float* __restrict__ v, const float* __restrict__ eigvec, float* __restrict__ hs)
{
    const int g = blockIdx.x;
    const int nbase = g * NPG + blockIdx.y * 128;
    __shared__ float evs[16][32];
    float acc[32];
#pragma unroll
    for (int k = 0; k < 32; k++) acc[k] = 0.f;
    for (int nt = 0; nt < 128; nt += 16) {
        __syncthreads();
        for (int i = threadIdx.x; i < 512; i += 256) {
            int nn = i >> 5, kk = i & 31;
            evs[nn][kk] = eigvec[(size_t)(nbase + nt + nn) * KEIG + kk];
        }
        __syncthreads();
#pragma unroll 4
        for (int nn = 0; nn < 16; nn++) {
            float hv = v[(size_t)(nbase + nt + nn) * CH + threadIdx.x];
#pragma unroll
            for (int k = 0; k < 32; k++) acc[k] += evs[nn][k] * hv;
        }
    }
    float* o = hs + (size_t)g * KEIG * CH + threadIdx.x;
#pragma unroll
    for (int k = 0; k < 32; k++) atomicAdd(o + k * CH, acc[k]);
}

// out16[g,n,d] = sum_v ev[g,n,v] * hs[g,v,d] * exp(-eigval[g,v]*taus[d>>2])
// (spec_scale fused into the hs load)
__global__ __launch_bounds__(256) void spec_reproj16_k(
    const float* __restrict__ eigvec, const float* __restrict__ hs,
    const float* __restrict__ eigval, const float* __restrict__ taus,
    _Float16* __restrict__ out16)
{
    const int g = blockIdx.x >> 4;
    const int nbase = g * NPG + (blockIdx.x & 15) * 64;
    const float tau = taus[threadIdx.x >> 2];
    float hsr[32];
    const float* hg = hs + (size_t)g * KEIG * CH + threadIdx.x;
#pragma unroll
    for (int k = 0; k < 32; k++)
        hsr[k] = hg[k * CH] * expf(-eigval[g * KEIG + k] * tau);
    __shared__ float evs[64][32];
    for (int i = threadIdx.x; i < 2048; i += 256) {
        int nn = i >> 5, kk = i & 31;
        evs[nn][kk] = eigvec[(size_t)(nbase + nn) * KEIG + kk];
    }
    __syncthreads();
    for (int nn = 0; nn < 64; nn++) {
        float a = 0.f;
#pragma unroll
        for (int k = 0; k < 32; k++) a += evs[nn][k] * hsr[k];
        out16[(size_t)(nbase + nn) * CH + threadIdx.x] = (_Float16)a;
    }
}

// ---------------------------------------------------------------------------
extern "C" void kernel_launch(void* const* d_in, const int* in_sizes, int n_in,
                              void* d_out, int out_size, void* d_ws, size_t ws_size,
                              hipStream_t stream)
{
    const float* x      = (const float*)d_in[0];
    const float* eigvec = (const float*)d_in[1];
    const float* eigval = (const float*)d_in[2];
    const float* taus   = (const float*)d_in[3];
    const float* enc_w  = (const float*)d_in[4];
    const float* enc_b  = (const float*)d_in[5];
    const float* self_w = (const float*)d_in[6];
    const float* self_b = (const float*)d_in[7];
    const float* nb_w   = (const float*)d_in[8];
    const float* nb_b   = (const float*)d_in[9];
    const float* dec_w  = (const float*)d_in[10];
    const float* dec_b  = (const float*)d_in[11];
    const float* lin_w  = (const float*)d_in[12];
    const float* lin_b  = (const float*)d_in[13];
    const int*   ei     = (const int*)d_in[14];
    (void)in_sizes; (void)n_in; (void)out_size; (void)ws_size;

    float* ws = (float*)d_ws;
    // Stream-ordered lifetimes (float-slot offsets):
    //  [0,        8388608)  x16          -> vf1[0:half] / h3
    //  [8388608, 16777216)  h0           -> vf1[half:]  / h3
    //  [16777216,25165824)  h1           -> hs (@16.7M) ; free tail
    //  [25165824,33554432)  agg          -> nr16 part
    //  [33554432,34275329)  CSR ints     -> nr16 part
    //  [25165824,37748736)  nr16 [NN,384] fp16 (dec out; agg+CSR dead)
    //  [37748752,37995024)  packed weights + lbias
    //  [37995024,46383632)  h2 [NN,256] fp16
    // high-water: 46,383,632 fl = 185.5 MB
    _Float16* x16 = (_Float16*)(ws);
    _Float16* h0  = (_Float16*)(ws + 8388608);
    _Float16* h1  = (_Float16*)(ws + 16777216);
    _Float16* agg = (_Float16*)(ws + 25165824);
    int* ibase  = (int*)(ws + 33554432);
    int* deg    = ibase;                 // NN
    int* off    = ibase + 65536;         // NN+1
    int* cursor = ibase + 131073;        // NN
    int* csr    = ibase + 196609;        // NEDGE (ends slot 34275329)
    _Float16* nr16 = (_Float16*)(ws + 25165824);  // [NN,384] fp16
    float* wb = ws + 37748752;
    _Float16* enc16 = (_Float16*)(wb);            // packed [256x256]
    _Float16* l1w   = (_Float16*)(wb + 32768);    // packed [256x512]
    _Float16* l2w   = (_Float16*)(wb + 98304);    // packed [256x512]
    _Float16* dec16 = (_Float16*)(wb + 163840);   // packed [384x256]
    _Float16* lin16 = (_Float16*)(wb + 212992);   // packed [256x256]
    float* lbias = wb + 245760;                   // [2,256] (ends wb+246272)
    _Float16* h2 = (_Float16*)(ws + 37995024);    // [NN,256] fp16
    float* vf1 = ws;                              // [NN,256] fp32 (x16,h0 dead)
    float* hs  = ws + 16777216;                   // [64,32,256] fp32 (h1 dead)
    float* h3  = vf1;                             // vf1 dead after spec_proj

    dim3 blk(256);

    // ---- prep ----
    cvt16_k<<<16384, blk, 0, stream>>>(x, x16);
    pack_k<256, 256, false><<<32, blk, 0, stream>>>(enc_w, nullptr, enc16);
    pack_k<256, 512, true ><<<64, blk, 0, stream>>>(self_w,         nb_w,         l1w);
    pack_k<256, 512, true ><<<64, blk, 0, stream>>>(self_w + 65536, nb_w + 65536, l2w);
    pack_k<384, 256, false><<<48, blk, 0, stream>>>(dec_w, nullptr, dec16);
    pack_k<256, 256, false><<<32, blk, 0, stream>>>(lin_w, nullptr, lin16);
    bcomb_k<<<2, blk, 0, stream>>>(self_b, nb_b, lbias);
    zero_k<<<64, blk, 0, stream>>>((float*)deg, (size_t)NN);
    hist_k<<<NEDGE / 256, blk, 0, stream>>>(ei, deg);
    scan_k<<<1, 1024, 0, stream>>>(deg, off, cursor);
    fill_k<<<NEDGE / 256, blk, 0, stream>>>(ei, cursor, csr);

    // ---- h0 = gelu(x @ enc_w + enc_b) ----
    mgemm_k<256, 256, false, true, false, false, true><<<dim3(1024), blk, 0, stream>>>(
        x16, nullptr, enc16, enc_b, nullptr, h0);

    // ---- GNN layer 1: h1 = gelu([h0,agg]@W + b) + h0 ----
    gather16_k<<<NN / 4, blk, 0, stream>>>(h0, off, csr, agg);
    mgemm_k<256, 512, true, true, true, false, true><<<dim3(1024), blk, 0, stream>>>(
        h0, agg, l1w, lbias, nullptr, h1);

    // ---- GNN layer 2: h0 = gelu([h1,agg]@W + b) + h1 ----
    gather16_k<<<NN / 4, blk, 0, stream>>>(h1, off, csr, agg);
    mgemm_k<256, 512, true, true, true, false, true><<<dim3(1024), blk, 0, stream>>>(
        h1, agg, l2w, lbias + 256, nullptr, h0);

    // ---- node_rep = h0 @ dec_w + dec_b  (fp16 out; agg+CSR dead) ----
    mgemm_k<384, 256, false, false, false, false, true><<<dim3(1024), dim3(384), 0, stream>>>(
        h0, nullptr, dec16, dec_b, nullptr, nr16);

    // ---- vf1 = Q . x  (x16,h0 dead) ----
    bundle_k<false><<<NN / 4, blk, 0, stream>>>(x, nr16, vf1);

    // ---- spectral filter (scale fused into reproj) ----
    zero_k<<<512, blk, 0, stream>>>(hs, (size_t)GG * KEIG * CH);
    spec_proj_k<<<dim3(GG, 8), blk, 0, stream>>>(vf1, eigvec, hs);
    spec_reproj16_k<<<GG * 16, blk, 0, stream>>>(eigvec, hs, eigval, taus, h2);

    // ---- h3 = h2 @ lin_w + lin_b  (fp32 out; vf1 dead) ----
    mgemm_k<256, 256, false, false, false, true, false><<<dim3(1024), blk, 0, stream>>>(
        h2, nullptr, lin16, lin_b, h3, nullptr);

    // ---- out = Q^T . h3 ----
    bundle_k<true><<<NN / 4, blk, 0, stream>>>(h3, nr16, (float*)d_out);
}

// Round 6
// 694.217 us; speedup vs baseline: 1.2415x; 1.0249x over previous
//
#include <hip/hip_runtime.h>
#include <math.h>

// Problem constants
#define NN      65536
#define GG      64
#define NPG     1024
#define KEIG    32
#define NBUN    64
#define BDIM    4
#define CH      256        // IN_CH == GNN_DIM == NB*BD
#define NBP     384
#define NEDGE   524288

using f16x8 = __attribute__((ext_vector_type(8))) _Float16;
using f16x4 = __attribute__((ext_vector_type(4))) _Float16;
using f32x4 = __attribute__((ext_vector_type(4))) float;

__device__ __forceinline__ float gelu_f(float x) {
    return 0.5f * x * (1.0f + erff(x * 0.70710678118654752440f));
}

// ---------------------------------------------------------------------------
// fp16 MFMA GEMM. R5 proved: per-instruction address scatter was the limiter;
// all-coalesced loads gave 106->72us. R5 counters: WRITE 80MB for 32MB logical
// (2.5x partial-line write amp from 32B scattered fp16 stores); B pipeline
// only 2-deep (VGPR 88) vs ~200-300cy L2 latency -> per-step stalls.
// R6 (same structure):
//  - 4-deep NAMED B prefetch, first 4 sets issued BEFORE the staging barrier.
//  - Coalesced C16 epilogue: scatter acc (bias/act/residual applied) into a
//    padded [64][NOUT+8] fp16 LDS tile (reusing Alds), barrier, then write
//    full rows lane-contiguous (dwordx4) -> kills write amplification.
//  - A: full-K panel staged once, XOR-swizzled LDS (verified R5).
// DUAL: A = concat_k(A1, A2), KTOT=512.
// RESA: + (float)A1[m,n] residual (requires NOUT==256).
// WF: write fp32 Cf (direct stores; fp32 is 64B-granular already).
// W16: write fp16 C16 via LDS-staged coalesced rows.
// Outputs disjoint from ALL inputs (graph-replay safety).
// ---------------------------------------------------------------------------
template<int NOUT, int KTOT, bool DUAL, bool ACT, bool RESA, bool WF, bool W16>
__global__ __launch_bounds__(NOUT, 2) void mgemm_k(
    const _Float16* __restrict__ A1, const _Float16* __restrict__ A2,
    const _Float16* __restrict__ Bp, const float* __restrict__ bias,
    float* __restrict__ Cf, _Float16* __restrict__ C16)
{
    constexpr int NT   = KTOT / 32;     // K-steps
    constexpr int ROWB = KTOT * 2;      // LDS bytes per A row
    constexpr int CPR  = KTOT / 8;      // 16B chunks per A row
    constexpr int CTS  = NOUT + 8;      // padded C-tile row stride (halfs)
    constexpr int AH   = 64 * KTOT;
    constexpr int CTH  = 64 * CTS;
    constexpr int LDSH = (W16 && CTH > AH) ? CTH : AH;
    __shared__ _Float16 Alds[LDSH];

    const int tid  = threadIdx.x;
    const int lane = tid & 63;
    const int wave = tid >> 6;          // wave owns cols wave*64..wave*64+63
    const int m0   = blockIdx.x * 64;   // block's 64 A rows

    const int r16 = lane & 15;          // fragment row / col within 16
    const int kc  = lane >> 4;          // k-chunk 0..3

    // B packed: chunk((wn*NT + t)*4 + q), lane-contiguous 16B each
    const _Float16* bpp = Bp + ((size_t)wave * NT * 2048) + lane * 8;

    f16x8 pa0, pa1, pa2, pa3, pb0, pb1, pb2, pb3;
    f16x8 pc0, pc1, pc2, pc3, pd0, pd1, pd2, pd3;

#define LDB(P0, P1, P2, P3, T)                                                 \
    {                                                                          \
        const _Float16* bq_ = bpp + (size_t)(T) * 2048;                        \
        P0 = *(const f16x8*)(bq_);                                             \
        P1 = *(const f16x8*)(bq_ + 512);                                       \
        P2 = *(const f16x8*)(bq_ + 1024);                                      \
        P3 = *(const f16x8*)(bq_ + 1536);                                      \
    }

    // issue B prefetch for steps 0..3 BEFORE staging (overlaps A HBM latency)
    LDB(pa0, pa1, pa2, pa3, 0)
    LDB(pb0, pb1, pb2, pb3, 1)
    LDB(pc0, pc1, pc2, pc3, 2)
    LDB(pd0, pd1, pd2, pd3, 3)

    // ---- stage full A panel once: coalesced loads -> regs -> swizzled LDS --
    constexpr int TOTC = 64 * CPR;
    constexpr int NSTG = TOTC / NOUT;   // full iters per thread
    {
        f16x8 stg[NSTG ? NSTG : 1];
#pragma unroll
        for (int j = 0; j < NSTG; j++) {
            const int idx = tid + j * NOUT;
            const int r = idx / CPR, c = idx - r * CPR;
            const _Float16* src = (DUAL && c >= CPR / 2)
                ? A2 + (size_t)(m0 + r) * 256 + (c - CPR / 2) * 8
                : A1 + (size_t)(m0 + r) * 256 + c * 8;
            stg[j] = *(const f16x8*)src;
        }
#pragma unroll
        for (int j = 0; j < NSTG; j++) {
            const int idx = tid + j * NOUT;
            const int r = idx / CPR, c = idx - r * CPR;
            *(f16x8*)((char*)Alds + ((r * ROWB + c * 16) ^ ((r & 7) << 4))) = stg[j];
        }
        if (TOTC % NOUT) {              // remainder (NOUT=384 case)
            const int idx = tid + NSTG * NOUT;
            if (idx < TOTC) {
                const int r = idx / CPR, c = idx - r * CPR;
                const _Float16* src = (DUAL && c >= CPR / 2)
                    ? A2 + (size_t)(m0 + r) * 256 + (c - CPR / 2) * 8
                    : A1 + (size_t)(m0 + r) * 256 + c * 8;
                f16x8 v = *(const f16x8*)src;
                *(f16x8*)((char*)Alds + ((r * ROWB + c * 16) ^ ((r & 7) << 4))) = v;
            }
        }
    }
    __syncthreads();

    f32x4 acc[4][4];
#pragma unroll
    for (int i = 0; i < 4; i++)
#pragma unroll
        for (int j = 0; j < 4; j++) acc[i][j] = 0.f;

#define MSTEP(OFF, P0, P1, P2, P3)                                             \
    {                                                                          \
        const char* ap_ = (const char*)Alds + (OFF);                           \
        f16x8 a0_ = *(const f16x8*)(ap_);                                      \
        f16x8 a1_ = *(const f16x8*)(ap_ + 16 * ROWB);                          \
        f16x8 a2_ = *(const f16x8*)(ap_ + 32 * ROWB);                          \
        f16x8 a3_ = *(const f16x8*)(ap_ + 48 * ROWB);                          \
        acc[0][0] = __builtin_amdgcn_mfma_f32_16x16x32_f16(a0_, P0, acc[0][0], 0, 0, 0); \
        acc[0][1] = __builtin_amdgcn_mfma_f32_16x16x32_f16(a0_, P1, acc[0][1], 0, 0, 0); \
        acc[0][2] = __builtin_amdgcn_mfma_f32_16x16x32_f16(a0_, P2, acc[0][2], 0, 0, 0); \
        acc[0][3] = __builtin_amdgcn_mfma_f32_16x16x32_f16(a0_, P3, acc[0][3], 0, 0, 0); \
        acc[1][0] = __builtin_amdgcn_mfma_f32_16x16x32_f16(a1_, P0, acc[1][0], 0, 0, 0); \
        acc[1][1] = __builtin_amdgcn_mfma_f32_16x16x32_f16(a1_, P1, acc[1][1], 0, 0, 0); \
        acc[1][2] = __builtin_amdgcn_mfma_f32_16x16x32_f16(a1_, P2, acc[1][2], 0, 0, 0); \
        acc[1][3] = __builtin_amdgcn_mfma_f32_16x16x32_f16(a1_, P3, acc[1][3], 0, 0, 0); \
        acc[2][0] = __builtin_amdgcn_mfma_f32_16x16x32_f16(a2_, P0, acc[2][0], 0, 0, 0); \
        acc[2][1] = __builtin_amdgcn_mfma_f32_16x16x32_f16(a2_, P1, acc[2][1], 0, 0, 0); \
        acc[2][2] = __builtin_amdgcn_mfma_f32_16x16x32_f16(a2_, P2, acc[2][2], 0, 0, 0); \
        acc[2][3] = __builtin_amdgcn_mfma_f32_16x16x32_f16(a2_, P3, acc[2][3], 0, 0, 0); \
        acc[3][0] = __builtin_amdgcn_mfma_f32_16x16x32_f16(a3_, P0, acc[3][0], 0, 0, 0); \
        acc[3][1] = __builtin_amdgcn_mfma_f32_16x16x32_f16(a3_, P1, acc[3][1], 0, 0, 0); \
        acc[3][2] = __builtin_amdgcn_mfma_f32_16x16x32_f16(a3_, P2, acc[3][2], 0, 0, 0); \
        acc[3][3] = __builtin_amdgcn_mfma_f32_16x16x32_f16(a3_, P3, acc[3][3], 0, 0, 0); \
    }

    int au = r16 * ROWB + kc * 16;      // unswizzled byte offset, step 0
    const int swz = (r16 & 7) << 4;
#pragma unroll
    for (int t = 0; t < NT; t += 4) {
        MSTEP((au      ) ^ swz, pa0, pa1, pa2, pa3)
        if (t + 4 < NT) LDB(pa0, pa1, pa2, pa3, t + 4)
        MSTEP((au +  64) ^ swz, pb0, pb1, pb2, pb3)
        if (t + 5 < NT) LDB(pb0, pb1, pb2, pb3, t + 5)
        MSTEP((au + 128) ^ swz, pc0, pc1, pc2, pc3)
        if (t + 6 < NT) LDB(pc0, pc1, pc2, pc3, t + 6)
        MSTEP((au + 192) ^ swz, pd0, pd1, pd2, pd3)
        if (t + 7 < NT) LDB(pd0, pd1, pd2, pd3, t + 7)
        au += 256;
    }
#undef LDB
#undef MSTEP

    // epilogue: C[m = quad*4+reg][n = lane&15] per 16x16 tile (m89 layout)
    const int rbase = (lane >> 4) * 4;
    const int ncol  = lane & 15;
    if constexpr (W16) {
        // coalesced path: scatter into padded LDS C-tile, then row-write
        __syncthreads();                // all waves done reading Alds
#pragma unroll
        for (int nt = 0; nt < 4; nt++) {
            const int n = wave * 64 + nt * 16 + ncol;
            const float bs = bias[n];
#pragma unroll
            for (int mt = 0; mt < 4; mt++) {
#pragma unroll
                for (int i = 0; i < 4; i++) {
                    const int mr = mt * 16 + rbase + i;
                    float v = acc[mt][nt][i] + bs;
                    if (ACT) v = gelu_f(v);
                    if (RESA) v += (float)A1[(size_t)(m0 + mr) * 256 + n];
                    Alds[mr * CTS + n] = (_Float16)v;
                }
            }
        }
        __syncthreads();
        constexpr int CPRN = NOUT / 8;  // 16B chunks per C row
        constexpr int CPT  = 64 * CPRN / NOUT;   // chunks per thread (= 8)
#pragma unroll
        for (int k2 = 0; k2 < CPT; k2++) {
            const int c = tid + k2 * NOUT;
            const int row = c / CPRN, col = c - row * CPRN;
            f16x8 v = *(const f16x8*)&Alds[row * CTS + col * 8];
            *(f16x8*)(C16 + (size_t)(m0 + row) * NOUT + col * 8) = v;
        }
    } else {
#pragma unroll
        for (int nt = 0; nt < 4; nt++) {
            const int n = wave * 64 + nt * 16 + ncol;
            const float bs = bias[n];
#pragma unroll
            for (int mt = 0; mt < 4; mt++) {
#pragma unroll
                for (int i = 0; i < 4; i++) {
                    const int m = m0 + mt * 16 + rbase + i;
                    float v = acc[mt][nt][i] + bs;
                    if (ACT) v = gelu_f(v);
                    if (RESA) v += (float)A1[(size_t)m * 256 + n];
                    if (WF) Cf[(size_t)m * NOUT + n] = v;
                }
            }
        }
    }
}

// ---------------------------------------------------------------------------
// Weight pack: fp32 W[k][n] (k-major, row stride NOUT) -> fragment-ordered
// fp16 chunks. Chunk cid = ((wn*NT + t)*4 + q)*64 + l holds 8 halfs:
// value[j] = W[t*32 + (l>>4)*8 + j][wn*64 + q*16 + (l&15)].
// DUAL: k >= 256 reads W2[k-256][n].
// ---------------------------------------------------------------------------
template<int NOUT, int KTOT, bool DUAL>
__global__ __launch_bounds__(256) void pack_k(
    const float* __restrict__ W1, const float* __restrict__ W2,
    _Float16* __restrict__ Bp)
{
    constexpr int NT = KTOT / 32;
    const int cid = blockIdx.x * 256 + threadIdx.x;
    if (cid >= NOUT * KTOT / 8) return;
    const int l  = cid & 63;
    const int q  = (cid >> 6) & 3;
    const int c2 = cid >> 8;            // wn*NT + t
    const int t  = c2 & (NT - 1);
    const int wn = c2 / NT;
    const int n  = wn * 64 + q * 16 + (l & 15);
    const int k0 = t * 32 + (l >> 4) * 8;
    f16x8 v;
#pragma unroll
    for (int j = 0; j < 8; j++) {
        const int k = k0 + j;
        float w = (DUAL && k >= 256) ? W2[(size_t)(k - 256) * NOUT + n]
                                     : W1[(size_t)k * NOUT + n];
        v[j] = (_Float16)w;
    }
    *(f16x8*)(Bp + (size_t)cid * 8) = v;
}

// ---------------------------------------------------------------------------
__global__ void zero_k(float* __restrict__ p, size_t n)
{
    size_t i = (size_t)blockIdx.x * blockDim.x + threadIdx.x;
    float4* p4 = (float4*)p;
    size_t n4 = n >> 2;
    for (size_t j = i; j < n4; j += (size_t)gridDim.x * blockDim.x)
        p4[j] = make_float4(0.f, 0.f, 0.f, 0.f);
}

// fp32 -> fp16 convert (4 elems/thread)
__global__ __launch_bounds__(256) void cvt16_k(
    const float* __restrict__ in, _Float16* __restrict__ out)
{
    size_t i = (size_t)blockIdx.x * 256 + threadIdx.x;
    float4 v = ((const float4*)in)[i];
    f16x4 o = { (_Float16)v.x, (_Float16)v.y, (_Float16)v.z, (_Float16)v.w };
    ((f16x4*)out)[i] = o;
}

__global__ void bcomb_k(const float* __restrict__ a, const float* __restrict__ b,
                        float* __restrict__ o)
{
    int i = blockIdx.x * 256 + threadIdx.x;
    if (i < 512) o[i] = a[i] + b[i];
}

// ---------------------------------------------------------------------------
// CSR build: histogram of dst, exclusive scan, cursor fill
// ---------------------------------------------------------------------------
__global__ __launch_bounds__(256) void hist_k(const int* __restrict__ ei, int* __restrict__ deg)
{
    int e = blockIdx.x * 256 + threadIdx.x;
    if (e < NEDGE) atomicAdd(&deg[ei[NEDGE + e]], 1);
}

__global__ __launch_bounds__(1024) void scan_k(
    const int* __restrict__ deg, int* __restrict__ off, int* __restrict__ cursor)
{
    __shared__ int sh[1024];
    const int tid = threadIdx.x;
    const int base = tid * 64;
    int s = 0;
#pragma unroll 8
    for (int i = 0; i < 64; i++) s += deg[base + i];
    const int mysum = s;
    sh[tid] = s;
    __syncthreads();
    for (int ofs = 1; ofs < 1024; ofs <<= 1) {
        int v = (tid >= ofs) ? sh[tid - ofs] : 0;
        __syncthreads();
        sh[tid] += v;
        __syncthreads();
    }
    int running = sh[tid] - mysum;
    for (int i = 0; i < 64; i++) {
        off[base + i] = running;
        cursor[base + i] = running;
        running += deg[base + i];
    }
    if (tid == 1023) off[NN] = running;
}

__global__ __launch_bounds__(256) void fill_k(
    const int* __restrict__ ei, int* __restrict__ cursor, int* __restrict__ csr)
{
    int e = blockIdx.x * 256 + threadIdx.x;
    if (e < NEDGE) {
        int d = ei[NEDGE + e];
        int pos = atomicAdd(&cursor[d], 1);
        csr[pos] = ei[e];   // src
    }
}

// ---------------------------------------------------------------------------
// Gather segment-sum over fp16 h: fp32 accum, fp16 out. 4 rows in flight.
// ---------------------------------------------------------------------------
__global__ __launch_bounds__(256) void gather16_k(
    const _Float16* __restrict__ h, const int* __restrict__ off,
    const int* __restrict__ csr, _Float16* __restrict__ agg)
{
    const int lane = threadIdx.x & 63;
    const int n = blockIdx.x * 4 + (threadIdx.x >> 6);
    const int s0 = off[n], s1 = off[n + 1];
    float a0 = 0.f, a1 = 0.f, a2 = 0.f, a3 = 0.f;
    int j = s0;
    for (; j + 3 < s1; j += 4) {
        const int i0 = csr[j], i1 = csr[j + 1], i2 = csr[j + 2], i3 = csr[j + 3];
        f16x4 v0 = ((const f16x4*)(h + (size_t)i0 * CH))[lane];
        f16x4 v1 = ((const f16x4*)(h + (size_t)i1 * CH))[lane];
        f16x4 v2 = ((const f16x4*)(h + (size_t)i2 * CH))[lane];
        f16x4 v3 = ((const f16x4*)(h + (size_t)i3 * CH))[lane];
        a0 += (float)v0[0] + (float)v1[0] + (float)v2[0] + (float)v3[0];
        a1 += (float)v0[1] + (float)v1[1] + (float)v2[1] + (float)v3[1];
        a2 += (float)v0[2] + (float)v1[2] + (float)v2[2] + (float)v3[2];
        a3 += (float)v0[3] + (float)v1[3] + (float)v2[3] + (float)v3[3];
    }
    for (; j < s1; j++) {
        f16x4 va = ((const f16x4*)(h + (size_t)csr[j] * CH))[lane];
        a0 += (float)va[0]; a1 += (float)va[1]; a2 += (float)va[2]; a3 += (float)va[3];
    }
    f16x4 o = { (_Float16)a0, (_Float16)a1, (_Float16)a2, (_Float16)a3 };
    ((f16x4*)(agg + (size_t)n * CH))[lane] = o;
}

// ---------------------------------------------------------------------------
// Householder Q from 6 fp16 params (BD=4: 3 reflectors)
// ---------------------------------------------------------------------------
__device__ __forceinline__ void make_Q(const _Float16* __restrict__ p, float Q[4][4])
{
#pragma unroll
    for (int i = 0; i < 4; i++)
#pragma unroll
        for (int j = 0; j < 4; j++) Q[i][j] = (i == j) ? 1.f : 0.f;
    int idx = 0;
#pragma unroll
    for (int j = 0; j < 3; j++) {
        float v[4] = {0.f, 0.f, 0.f, 0.f};
        v[j] = 1.f;
#pragma unroll
        for (int t = 0; t < 4; t++)
            if (t > j) v[t] = (float)p[idx + t - (j + 1)];
        idx += 3 - j;
        float nrm = v[0]*v[0] + v[1]*v[1] + v[2]*v[2] + v[3]*v[3];
        float s = 2.f / nrm;
#pragma unroll
        for (int i = 0; i < 4; i++) {
            float qv = Q[i][0]*v[0] + Q[i][1]*v[1] + Q[i][2]*v[2] + Q[i][3]*v[3];
            float t0 = s * qv;
#pragma unroll
            for (int c = 0; c < 4; c++) Q[i][c] -= t0 * v[c];
        }
    }
}

// Bundle transform: block = 4 nodes x 64 bundles; node_rep is fp16
template<bool TRANS>
__global__ __launch_bounds__(256) void bundle_k(
    const float* __restrict__ vin, const _Float16* __restrict__ nr,
    float* __restrict__ out)
{
    __shared__ _Float16 pb[4 * NBP];
    const int n0 = blockIdx.x * 4;
    for (int i = threadIdx.x; i < 4 * NBP; i += 256)
        pb[i] = nr[(size_t)n0 * NBP + i];
    __syncthreads();
    const int ln = threadIdx.x >> 6;
    const int b  = threadIdx.x & 63;
    const int n  = n0 + ln;
    float Q[4][4];
    make_Q(&pb[ln * NBP + b * 6], Q);
    float4 xv = ((const float4*)(vin + (size_t)n * CH))[b];
    float in0 = xv.x, in1 = xv.y, in2 = xv.z, in3 = xv.w;
    float4 o;
    if constexpr (!TRANS) {
        o.x = Q[0][0]*in0 + Q[0][1]*in1 + Q[0][2]*in2 + Q[0][3]*in3;
        o.y = Q[1][0]*in0 + Q[1][1]*in1 + Q[1][2]*in2 + Q[1][3]*in3;
        o.z = Q[2][0]*in0 + Q[2][1]*in1 + Q[2][2]*in2 + Q[2][3]*in3;
        o.w = Q[3][0]*in0 + Q[3][1]*in1 + Q[3][2]*in2 + Q[3][3]*in3;
    } else {
        o.x = Q[0][0]*in0 + Q[1][0]*in1 + Q[2][0]*in2 + Q[3][0]*in3;
        o.y = Q[0][1]*in0 + Q[1][1]*in1 + Q[2][1]*in2 + Q[3][1]*in3;
        o.z = Q[0][2]*in0 + Q[1][2]*in1 + Q[2][2]*in2 + Q[3][2]*in3;
        o.w = Q[0][3]*in0 + Q[1][3]*in1 + Q[2][3]*in2 + Q[3][3]*in3;
    }
    ((float4*)(out + (size_t)n * CH))[b] = o;
}

// ---------------------------------------------------------------------------
// Spectral kernels
// ---------------------------------------------------------------------------
__global__ __launch_bounds__(256) void spec_proj_k(
    const float* __restrict__ v, const float* __restrict__ eigvec, float* __restrict__ hs)
{
    const int g = blockIdx.x;
    const int nbase = g * NPG + blockIdx.y * 128;
    __shared__ float evs[16][32];
    float acc[32];
#pragma unroll
    for (int k = 0; k < 32; k++) acc[k] = 0.f;
    for (int nt = 0; nt < 128; nt += 16) {
        __syncthreads();
        for (int i = threadIdx.x; i < 512; i += 256) {
            int nn = i >> 5, kk = i & 31;
            evs[nn][kk] = eigvec[(size_t)(nbase + nt + nn) * KEIG + kk];
        }
        __syncthreads();
#pragma unroll 4
        for (int nn = 0; nn < 16; nn++) {
            float hv = v[(size_t)(nbase + nt + nn) * CH + threadIdx.x];
#pragma unroll
            for (int k = 0; k < 32; k++) acc[k] += evs[nn][k] * hv;
        }
    }
    float* o = hs + (size_t)g * KEIG * CH + threadIdx.x;
#pragma unroll
    for (int k = 0; k < 32; k++) atomicAdd(o + k * CH, acc[k]);
}

// out16[g,n,d] = sum_v ev[g,n,v] * hs[g,v,d] * exp(-eigval[g,v]*taus[d>>2])
// (spec_scale fused into the hs load)
__global__ __launch_bounds__(256) void spec_reproj16_k(
    const float* __restrict__ eigvec, const float* __restrict__ hs,
    const float* __restrict__ eigval, const float* __restrict__ taus,
    _Float16* __restrict__ out16)
{
    const int g = blockIdx.x >> 4;
    const int nbase = g * NPG + (blockIdx.x & 15) * 64;
    const float tau = taus[threadIdx.x >> 2];
    float hsr[32];
    const float* hg = hs + (size_t)g * KEIG * CH + threadIdx.x;
#pragma unroll
    for (int k = 0; k < 32; k++)
        hsr[k] = hg[k * CH] * expf(-eigval[g * KEIG + k] * tau);
    __shared__ float evs[64][32];
    for (int i = threadIdx.x; i < 2048; i += 256) {
        int nn = i >> 5, kk = i & 31;
        evs[nn][kk] = eigvec[(size_t)(nbase + nn) * KEIG + kk];
    }
    __syncthreads();
    for (int nn = 0; nn < 64; nn++) {
        float a = 0.f;
#pragma unroll
        for (int k = 0; k < 32; k++) a += evs[nn][k] * hsr[k];
        out16[(size_t)(nbase + nn) * CH + threadIdx.x] = (_Float16)a;
    }
}

// ---------------------------------------------------------------------------
extern "C" void kernel_launch(void* const* d_in, const int* in_sizes, int n_in,
                              void* d_out, int out_size, void* d_ws, size_t ws_size,
                              hipStream_t stream)
{
    const float* x      = (const float*)d_in[0];
    const float* eigvec = (const float*)d_in[1];
    const float* eigval = (const float*)d_in[2];
    const float* taus   = (const float*)d_in[3];
    const float* enc_w  = (const float*)d_in[4];
    const float* enc_b  = (const float*)d_in[5];
    const float* self_w = (const float*)d_in[6];
    const float* self_b = (const float*)d_in[7];
    const float* nb_w   = (const float*)d_in[8];
    const float* nb_b   = (const float*)d_in[9];
    const float* dec_w  = (const float*)d_in[10];
    const float* dec_b  = (const float*)d_in[11];
    const float* lin_w  = (const float*)d_in[12];
    const float* lin_b  = (const float*)d_in[13];
    const int*   ei     = (const int*)d_in[14];
    (void)in_sizes; (void)n_in; (void)out_size; (void)ws_size;

    float* ws = (float*)d_ws;
    // Stream-ordered lifetimes (float-slot offsets):
    //  [0,        8388608)  x16          -> vf1[0:half] / h3
    //  [8388608, 16777216)  h0           -> vf1[half:]  / h3
    //  [16777216,25165824)  h1           -> hs (@16.7M) ; free tail
    //  [25165824,33554432)  agg          -> nr16 part
    //  [33554432,34275329)  CSR ints     -> nr16 part
    //  [25165824,37748736)  nr16 [NN,384] fp16 (dec out; agg+CSR dead)
    //  [37748752,37995024)  packed weights + lbias
    //  [37995024,46383632)  h2 [NN,256] fp16
    // high-water: 46,383,632 fl = 185.5 MB
    _Float16* x16 = (_Float16*)(ws);
    _Float16* h0  = (_Float16*)(ws + 8388608);
    _Float16* h1  = (_Float16*)(ws + 16777216);
    _Float16* agg = (_Float16*)(ws + 25165824);
    int* ibase  = (int*)(ws + 33554432);
    int* deg    = ibase;                 // NN
    int* off    = ibase + 65536;         // NN+1
    int* cursor = ibase + 131073;        // NN
    int* csr    = ibase + 196609;        // NEDGE (ends slot 34275329)
    _Float16* nr16 = (_Float16*)(ws + 25165824);  // [NN,384] fp16
    float* wb = ws + 37748752;
    _Float16* enc16 = (_Float16*)(wb);            // packed [256x256]
    _Float16* l1w   = (_Float16*)(wb + 32768);    // packed [256x512]
    _Float16* l2w   = (_Float16*)(wb + 98304);    // packed [256x512]
    _Float16* dec16 = (_Float16*)(wb + 163840);   // packed [384x256]
    _Float16* lin16 = (_Float16*)(wb + 212992);   // packed [256x256]
    float* lbias = wb + 245760;                   // [2,256] (ends wb+246272)
    _Float16* h2 = (_Float16*)(ws + 37995024);    // [NN,256] fp16
    float* vf1 = ws;                              // [NN,256] fp32 (x16,h0 dead)
    float* hs  = ws + 16777216;                   // [64,32,256] fp32 (h1 dead)
    float* h3  = vf1;                             // vf1 dead after spec_proj

    dim3 blk(256);

    // ---- prep ----
    cvt16_k<<<16384, blk, 0, stream>>>(x, x16);
    pack_k<256, 256, false><<<32, blk, 0, stream>>>(enc_w, nullptr, enc16);
    pack_k<256, 512, true ><<<64, blk, 0, stream>>>(self_w,         nb_w,         l1w);
    pack_k<256, 512, true ><<<64, blk, 0, stream>>>(self_w + 65536, nb_w + 65536, l2w);
    pack_k<384, 256, false><<<48, blk, 0, stream>>>(dec_w, nullptr, dec16);
    pack_k<256, 256, false><<<32, blk, 0, stream>>>(lin_w, nullptr, lin16);
    bcomb_k<<<2, blk, 0, stream>>>(self_b, nb_b, lbias);
    zero_k<<<64, blk, 0, stream>>>((float*)deg, (size_t)NN);
    hist_k<<<NEDGE / 256, blk, 0, stream>>>(ei, deg);
    scan_k<<<1, 1024, 0, stream>>>(deg, off, cursor);
    fill_k<<<NEDGE / 256, blk, 0, stream>>>(ei, cursor, csr);

    // ---- h0 = gelu(x @ enc_w + enc_b) ----
    mgemm_k<256, 256, false, true, false, false, true><<<dim3(1024), blk, 0, stream>>>(
        x16, nullptr, enc16, enc_b, nullptr, h0);

    // ---- GNN layer 1: h1 = gelu([h0,agg]@W + b) + h0 ----
    gather16_k<<<NN / 4, blk, 0, stream>>>(h0, off, csr, agg);
    mgemm_k<256, 512, true, true, true, false, true><<<dim3(1024), blk, 0, stream>>>(
        h0, agg, l1w, lbias, nullptr, h1);

    // ---- GNN layer 2: h0 = gelu([h1,agg]@W + b) + h1 ----
    gather16_k<<<NN / 4, blk, 0, stream>>>(h1, off, csr, agg);
    mgemm_k<256, 512, true, true, true, false, true><<<dim3(1024), blk, 0, stream>>>(
        h1, agg, l2w, lbias + 256, nullptr, h0);

    // ---- node_rep = h0 @ dec_w + dec_b  (fp16 out; agg+CSR dead) ----
    mgemm_k<384, 256, false, false, false, false, true><<<dim3(1024), dim3(384), 0, stream>>>(
        h0, nullptr, dec16, dec_b, nullptr, nr16);

    // ---- vf1 = Q . x  (x16,h0 dead) ----
    bundle_k<false><<<NN / 4, blk, 0, stream>>>(x, nr16, vf1);

    // ---- spectral filter (scale fused into reproj) ----
    zero_k<<<512, blk, 0, stream>>>(hs, (size_t)GG * KEIG * CH);
    spec_proj_k<<<dim3(GG, 8), blk, 0, stream>>>(vf1, eigvec, hs);
    spec_reproj16_k<<<GG * 16, blk, 0, stream>>>(eigvec, hs, eigval, taus, h2);

    // ---- h3 = h2 @ lin_w + lin_b  (fp32 out; vf1 dead) ----
    mgemm_k<256, 256, false, false, false, true, false><<<dim3(1024), blk, 0, stream>>>(
        h2, nullptr, lin16, lin_b, h3, nullptr);

    // ---- out = Q^T . h3 ----
    bundle_k<true><<<NN / 4, blk, 0, stream>>>(h3, nr16, (float*)d_out);
}